// Round 1
// baseline (1227.540 us; speedup 1.0000x reference)
//
#include <hip/hip_runtime.h>
#include <hip/hip_bf16.h>
#include <math.h>

#define BN_EPS 1e-5f

// ---------------- class-embedding MLP: 16 -> 64 (BN+GELU) -> 128, constant over points ----------------
__global__ __launch_bounds__(512) void cls_kernel(const int* __restrict__ lbl,
                                                  const float* __restrict__ Wc1,
                                                  const float* __restrict__ gc,
                                                  const float* __restrict__ bc,
                                                  const float* __restrict__ Wc2,
                                                  float* __restrict__ cls_vec) {
    __shared__ float h[4 * 64];
    __shared__ float act[4 * 64];
    int tid = threadIdx.x;
    if (tid < 256) {
        int b = tid >> 6, c = tid & 63;
        h[b * 64 + c] = Wc1[c * 16 + lbl[b]];
    }
    __syncthreads();
    if (tid < 64) {
        int c = tid;
        float m = 0.f;
        for (int b = 0; b < 4; b++) m += h[b * 64 + c];
        m *= 0.25f;
        float v = 0.f;
        for (int b = 0; b < 4; b++) { float d = h[b * 64 + c] - m; v += d * d; }
        v *= 0.25f;
        float sc = gc[c] * rsqrtf(v + BN_EPS);
        float sh = bc[c] - m * sc;
        for (int b = 0; b < 4; b++) {
            float x = h[b * 64 + c] * sc + sh;
            act[b * 64 + c] = 0.5f * x * (1.f + erff(x * 0.70710678118654752f));
        }
    }
    __syncthreads();
    int b = tid >> 7, o = tid & 127;  // 512 threads = 4 * 128
    float s = 0.f;
    for (int c = 0; c < 64; c++) s += Wc2[o * 64 + c] * act[b * 64 + c];
    cls_vec[b * 128 + o] = s;
}

// ---------------- 3-NN: for each dense point find 3 nearest sparse points ----------------
__global__ __launch_bounds__(256) void knn_kernel(const float* __restrict__ pd,
                                                  const float* __restrict__ ps,
                                                  int N1, int N2,
                                                  int* __restrict__ idx,
                                                  float* __restrict__ w) {
    const int CHUNK = 256;
    __shared__ float sp[CHUNK * 3];
    int b = blockIdx.y;
    int n = blockIdx.x * 256 + threadIdx.x;
    float px = pd[((size_t)b * N1 + n) * 3 + 0];
    float py = pd[((size_t)b * N1 + n) * 3 + 1];
    float pz = pd[((size_t)b * N1 + n) * 3 + 2];
    float d0 = 3.4e38f, d1 = 3.4e38f, d2 = 3.4e38f;
    int i0 = 0, i1 = 0, i2 = 0;
    for (int base = 0; base < N2; base += CHUNK) {
        int cnt = min(CHUNK, N2 - base);
        for (int t = threadIdx.x; t < cnt * 3; t += 256)
            sp[t] = ps[((size_t)b * N2 + base) * 3 + t];
        __syncthreads();
        for (int j = 0; j < cnt; j++) {
            float dx = px - sp[j * 3 + 0];
            float dy = py - sp[j * 3 + 1];
            float dz = pz - sp[j * 3 + 2];
            float d = dx * dx + dy * dy + dz * dz;
            int gi = base + j;
            if (d < d0) { d2 = d1; i2 = i1; d1 = d0; i1 = i0; d0 = d; i0 = gi; }
            else if (d < d1) { d2 = d1; i2 = i1; d1 = d; i1 = gi; }
            else if (d < d2) { d2 = d; i2 = gi; }
        }
        __syncthreads();
    }
    float w0 = 1.f / (d0 + 1e-8f), w1 = 1.f / (d1 + 1e-8f), w2 = 1.f / (d2 + 1e-8f);
    float s = 1.f / (w0 + w1 + w2);
    size_t o = ((size_t)b * N1 + n) * 3;
    idx[o] = i0; idx[o + 1] = i1; idx[o + 2] = i2;
    w[o] = w0 * s; w[o + 1] = w1 * s; w[o + 2] = w2 * s;
}

// ---------------- build x = concat(skip(+cls), interp(f_sparse)) : (B, Ctot, N1) ----------------
__global__ __launch_bounds__(256) void build_x_kernel(const float* __restrict__ skip,
                                                      const float* __restrict__ fs,
                                                      const float* __restrict__ cls_vec,
                                                      const int* __restrict__ idx,
                                                      const float* __restrict__ w,
                                                      float* __restrict__ x,
                                                      int Cskip, int Ctot, int Csp, int N1, int N2) {
    size_t gid = (size_t)blockIdx.x * 256 + threadIdx.x;
    size_t total = (size_t)4 * Ctot * N1;
    if (gid >= total) return;
    int n = gid % N1;
    int c = (gid / N1) % Ctot;
    int b = gid / ((size_t)N1 * Ctot);
    float val;
    if (c < Cskip) {
        val = skip[((size_t)b * Cskip + c) * N1 + n];
        if (cls_vec) val += cls_vec[b * 128 + c];
    } else {
        int c2 = c - Cskip;
        size_t o = ((size_t)b * N1 + n) * 3;
        const float* fb = fs + ((size_t)b * Csp + c2) * N2;
        val = w[o] * fb[idx[o]] + w[o + 1] * fb[idx[o + 1]] + w[o + 2] * fb[idx[o + 2]];
    }
    x[gid] = val;
}

// ---------------- fp32 GEMM: Y[b,m,n] = sum_k W[m,k] * X[b,k,n]   (M,N mult of 64, K mult of 16) ----------------
__global__ __launch_bounds__(256) void gemm_kernel(const float* __restrict__ W,
                                                   const float* __restrict__ X,
                                                   float* __restrict__ Y,
                                                   int M, int K, int N) {
    const float* Xb = X + (size_t)blockIdx.z * K * N;
    float* Yb = Y + (size_t)blockIdx.z * M * N;
    int bm = blockIdx.y * 64, bn = blockIdx.x * 64;
    __shared__ float As[16][65];
    __shared__ float Bs[16][65];
    float acc[4][4] = {};
    int tx = threadIdx.x % 16, ty = threadIdx.x / 16;
    for (int k0 = 0; k0 < K; k0 += 16) {
        for (int e = threadIdx.x; e < 1024; e += 256) {
            int m = e >> 4, k = e & 15;
            As[k][m] = W[(size_t)(bm + m) * K + k0 + k];
        }
        for (int e = threadIdx.x; e < 1024; e += 256) {
            int k = e >> 6, n = e & 63;
            Bs[k][n] = Xb[(size_t)(k0 + k) * N + bn + n];
        }
        __syncthreads();
#pragma unroll
        for (int k = 0; k < 16; k++) {
            float a[4], bv[4];
#pragma unroll
            for (int i = 0; i < 4; i++) a[i] = As[k][ty * 4 + i];
#pragma unroll
            for (int j = 0; j < 4; j++) bv[j] = Bs[k][tx * 4 + j];
#pragma unroll
            for (int i = 0; i < 4; i++)
#pragma unroll
                for (int j = 0; j < 4; j++) acc[i][j] += a[i] * bv[j];
        }
        __syncthreads();
    }
    for (int i = 0; i < 4; i++)
        for (int j = 0; j < 4; j++)
            Yb[(size_t)(bm + ty * 4 + i) * N + bn + tx * 4 + j] = acc[i][j];
}

// ---------------- BN stats per channel over (B, N): scale/shift ----------------
__global__ __launch_bounds__(256) void bn_stats_kernel(const float* __restrict__ X,
                                                       const float* __restrict__ g,
                                                       const float* __restrict__ bb,
                                                       float* __restrict__ scale,
                                                       float* __restrict__ shift,
                                                       int C, int N) {
    int c = blockIdx.x;
    float s = 0.f, s2 = 0.f;
    int total = 4 * N;
    for (int i = threadIdx.x; i < total; i += 256) {
        int b = i / N, n = i % N;
        float x = X[((size_t)b * C + c) * N + n];
        s += x; s2 += x * x;
    }
    __shared__ float ls[256], ls2[256];
    ls[threadIdx.x] = s; ls2[threadIdx.x] = s2;
    __syncthreads();
    for (int o = 128; o > 0; o >>= 1) {
        if (threadIdx.x < o) { ls[threadIdx.x] += ls[threadIdx.x + o]; ls2[threadIdx.x] += ls2[threadIdx.x + o]; }
        __syncthreads();
    }
    if (threadIdx.x == 0) {
        float inv = 1.f / (float)total;
        float m = ls[0] * inv;
        float v = ls2[0] * inv - m * m;
        v = fmaxf(v, 0.f);
        float sc = g[c] * rsqrtf(v + BN_EPS);
        scale[c] = sc;
        shift[c] = bb[c] - m * sc;
    }
}

__global__ __launch_bounds__(256) void bn_apply_kernel(float* __restrict__ X,
                                                       const float* __restrict__ scale,
                                                       const float* __restrict__ shift,
                                                       int C, int N) {
    size_t gid = (size_t)blockIdx.x * 256 + threadIdx.x;
    size_t total = (size_t)4 * C * N;
    if (gid >= total) return;
    int c = (gid / N) % C;
    X[gid] = X[gid] * scale[c] + shift[c];
}

extern "C" void kernel_launch(void* const* d_in, const int* in_sizes, int n_in,
                              void* d_out, int out_size, void* d_ws, size_t ws_size,
                              hipStream_t stream) {
    const float* p1 = (const float*)d_in[1];
    const float* p2 = (const float*)d_in[2];
    const float* p3 = (const float*)d_in[3];
    const float* p4 = (const float*)d_in[4];
    const float* f1 = (const float*)d_in[5];
    const float* f2 = (const float*)d_in[6];
    const float* f3 = (const float*)d_in[7];
    const float* f4 = (const float*)d_in[8];
    const int* cls = (const int*)d_in[9];
    const float* Wc1 = (const float*)d_in[10];
    const float* gc  = (const float*)d_in[11];
    const float* bc  = (const float*)d_in[12];
    const float* Wc2 = (const float*)d_in[13];
    const float* Ws2a = (const float*)d_in[14];
    const float* gs2a = (const float*)d_in[15];
    const float* bs2a = (const float*)d_in[16];
    const float* Ws2b = (const float*)d_in[17];
    const float* gs2b = (const float*)d_in[18];
    const float* bs2b = (const float*)d_in[19];
    const float* Ws1a = (const float*)d_in[20];
    const float* gs1a = (const float*)d_in[21];
    const float* bs1a = (const float*)d_in[22];
    const float* Ws1b = (const float*)d_in[23];
    const float* gs1b = (const float*)d_in[24];
    const float* bs1b = (const float*)d_in[25];
    const float* Ws0a = (const float*)d_in[26];
    const float* gs0a = (const float*)d_in[27];
    const float* bs0a = (const float*)d_in[28];
    const float* Ws0b = (const float*)d_in[29];
    const float* gs0b = (const float*)d_in[30];
    const float* bs0b = (const float*)d_in[31];

    char* ws = (char*)d_ws;
    float* XS = (float*)ws;                         // 12.6M floats (max 4*384*8192)
    float* YA = (float*)(ws + 50331648);            // 4M floats
    float* FN = (float*)(ws + 50331648 + 16777216); // 2M floats
    int*   IDX = (int*)(ws + 50331648 + 16777216 + 8388608);
    float* WGT = (float*)(ws + 50331648 + 16777216 + 8388608 + 393216);
    float* CLSV = (float*)(ws + 50331648 + 16777216 + 8388608 + 2 * 393216);
    float* SC = (float*)(ws + 50331648 + 16777216 + 8388608 + 2 * 393216 + 2048);
    float* SH = (float*)(ws + 50331648 + 16777216 + 8388608 + 2 * 393216 + 4096);

    float* OUT = (float*)d_out;

    // class embedding
    cls_kernel<<<1, 512, 0, stream>>>(cls, Wc1, gc, bc, Wc2, CLSV);

    // ---- stage s2: p3 (512) <- p4 (128), f3(512ch) + interp(f4,1024ch) -> 512ch
    knn_kernel<<<dim3(512 / 256, 4), 256, 0, stream>>>(p3, p4, 512, 128, IDX, WGT);
    {
        size_t tot = (size_t)4 * 1536 * 512;
        build_x_kernel<<<(tot + 255) / 256, 256, 0, stream>>>(f3, f4, nullptr, IDX, WGT, XS, 512, 1536, 1024, 512, 128);
    }
    gemm_kernel<<<dim3(512 / 64, 512 / 64, 4), 256, 0, stream>>>(Ws2a, XS, YA, 512, 1536, 512);
    bn_stats_kernel<<<512, 256, 0, stream>>>(YA, gs2a, bs2a, SC, SH, 512, 512);
    bn_apply_kernel<<<((size_t)4 * 512 * 512 + 255) / 256, 256, 0, stream>>>(YA, SC, SH, 512, 512);
    gemm_kernel<<<dim3(512 / 64, 512 / 64, 4), 256, 0, stream>>>(Ws2b, YA, FN, 512, 512, 512);
    bn_stats_kernel<<<512, 256, 0, stream>>>(FN, gs2b, bs2b, SC, SH, 512, 512);
    bn_apply_kernel<<<((size_t)4 * 512 * 512 + 255) / 256, 256, 0, stream>>>(FN, SC, SH, 512, 512);

    // ---- stage s1: p2 (2048) <- p3 (512), f2(256ch) + interp(f3n,512ch) -> 256ch
    knn_kernel<<<dim3(2048 / 256, 4), 256, 0, stream>>>(p2, p3, 2048, 512, IDX, WGT);
    {
        size_t tot = (size_t)4 * 768 * 2048;
        build_x_kernel<<<(tot + 255) / 256, 256, 0, stream>>>(f2, FN, nullptr, IDX, WGT, XS, 256, 768, 512, 2048, 512);
    }
    gemm_kernel<<<dim3(2048 / 64, 256 / 64, 4), 256, 0, stream>>>(Ws1a, XS, YA, 256, 768, 2048);
    bn_stats_kernel<<<256, 256, 0, stream>>>(YA, gs1a, bs1a, SC, SH, 256, 2048);
    bn_apply_kernel<<<((size_t)4 * 256 * 2048 + 255) / 256, 256, 0, stream>>>(YA, SC, SH, 256, 2048);
    gemm_kernel<<<dim3(2048 / 64, 256 / 64, 4), 256, 0, stream>>>(Ws1b, YA, FN, 256, 256, 2048);
    bn_stats_kernel<<<256, 256, 0, stream>>>(FN, gs1b, bs1b, SC, SH, 256, 2048);
    bn_apply_kernel<<<((size_t)4 * 256 * 2048 + 255) / 256, 256, 0, stream>>>(FN, SC, SH, 256, 2048);

    // ---- stage s0: p1 (8192) <- p2 (2048), (f1+cls)(128ch) + interp(f2n,256ch) -> 128ch
    knn_kernel<<<dim3(8192 / 256, 4), 256, 0, stream>>>(p1, p2, 8192, 2048, IDX, WGT);
    {
        size_t tot = (size_t)4 * 384 * 8192;
        build_x_kernel<<<(tot + 255) / 256, 256, 0, stream>>>(f1, FN, CLSV, IDX, WGT, XS, 128, 384, 256, 8192, 2048);
    }
    gemm_kernel<<<dim3(8192 / 64, 128 / 64, 4), 256, 0, stream>>>(Ws0a, XS, YA, 128, 384, 8192);
    bn_stats_kernel<<<128, 256, 0, stream>>>(YA, gs0a, bs0a, SC, SH, 128, 8192);
    bn_apply_kernel<<<((size_t)4 * 128 * 8192 + 255) / 256, 256, 0, stream>>>(YA, SC, SH, 128, 8192);
    gemm_kernel<<<dim3(8192 / 64, 128 / 64, 4), 256, 0, stream>>>(Ws0b, YA, OUT, 128, 128, 8192);
    bn_stats_kernel<<<128, 256, 0, stream>>>(OUT, gs0b, bs0b, SC, SH, 128, 8192);
    bn_apply_kernel<<<((size_t)4 * 128 * 8192 + 255) / 256, 256, 0, stream>>>(OUT, SC, SH, 128, 8192);
}

// Round 2
// 474.642 us; speedup vs baseline: 2.5862x; 2.5862x over previous
//
#include <hip/hip_runtime.h>
#include <math.h>

#define BN_EPS 1e-5f

typedef float f32x4 __attribute__((ext_vector_type(4)));
typedef short s16x8 __attribute__((ext_vector_type(8)));
typedef short s16x4 __attribute__((ext_vector_type(4)));

__device__ __forceinline__ unsigned short f2bf(float f) {
    unsigned u = __builtin_bit_cast(unsigned, f);
    u = u + 0x7FFFu + ((u >> 16) & 1u);
    return (unsigned short)(u >> 16);
}
__device__ __forceinline__ float bf2f(unsigned short s) {
    unsigned u = ((unsigned)s) << 16;
    return __builtin_bit_cast(float, u);
}

// ---------------- class-embedding MLP: 16 -> 64 (BN+GELU) -> 128 ----------------
__global__ __launch_bounds__(512) void cls_kernel(const int* __restrict__ lbl,
                                                  const float* __restrict__ Wc1,
                                                  const float* __restrict__ gc,
                                                  const float* __restrict__ bc,
                                                  const float* __restrict__ Wc2,
                                                  float* __restrict__ cls_vec) {
    __shared__ float h[4 * 64];
    __shared__ float act[4 * 64];
    int tid = threadIdx.x;
    if (tid < 256) {
        int b = tid >> 6, c = tid & 63;
        h[b * 64 + c] = Wc1[c * 16 + lbl[b]];
    }
    __syncthreads();
    if (tid < 64) {
        int c = tid;
        float m = 0.f;
        for (int b = 0; b < 4; b++) m += h[b * 64 + c];
        m *= 0.25f;
        float v = 0.f;
        for (int b = 0; b < 4; b++) { float d = h[b * 64 + c] - m; v += d * d; }
        v *= 0.25f;
        float sc = gc[c] * rsqrtf(v + BN_EPS);
        float sh = bc[c] - m * sc;
        for (int b = 0; b < 4; b++) {
            float x = h[b * 64 + c] * sc + sh;
            act[b * 64 + c] = 0.5f * x * (1.f + erff(x * 0.70710678118654752f));
        }
    }
    __syncthreads();
    int b = tid >> 7, o = tid & 127;
    float s = 0.f;
    for (int c = 0; c < 64; c++) s += Wc2[o * 64 + c] * act[b * 64 + c];
    cls_vec[b * 128 + o] = s;
}

// ---------------- transpose (B,C,N) fp32 -> (B,N,C) bf16, optional per-channel add ----------------
__global__ __launch_bounds__(256) void transpose_cp(const float* __restrict__ in,
                                                    unsigned short* __restrict__ out,
                                                    const float* __restrict__ addv,
                                                    int C, int N) {
    __shared__ float t[32][33];
    int b = blockIdx.z;
    int n0 = blockIdx.x * 32, c0 = blockIdx.y * 32;
    int i = threadIdx.x & 31, jj = threadIdx.x >> 5;
#pragma unroll
    for (int j = jj; j < 32; j += 8) {
        float v = in[((size_t)b * C + c0 + j) * N + n0 + i];
        if (addv) v += addv[b * C + c0 + j];
        t[j][i] = v;
    }
    __syncthreads();
    int j2 = threadIdx.x & 31, i2b = threadIdx.x >> 5;
#pragma unroll
    for (int i2 = i2b; i2 < 32; i2 += 8)
        out[((size_t)b * N + n0 + i2) * C + c0 + j2] = f2bf(t[j2][i2]);
}

// ---------------- 3-NN: 8 lanes per dense point, butterfly merge ----------------
#define KLESS(d, i, dd, ii) ((d) < (dd) || ((d) == (dd) && (i) < (ii)))
__global__ __launch_bounds__(256) void knn_kernel(const float* __restrict__ pd,
                                                  const float* __restrict__ ps,
                                                  int N1, int N2,
                                                  int* __restrict__ idx,
                                                  float* __restrict__ w) {
    __shared__ float sp[2048 * 3];
    int b = blockIdx.y;
    int tid = threadIdx.x;
    for (int t = tid; t < N2 * 3; t += 256) sp[t] = ps[(size_t)b * N2 * 3 + t];
    __syncthreads();
    int sub = tid & 7;
    int n = blockIdx.x * 32 + (tid >> 3);
    size_t pb = ((size_t)b * N1 + n) * 3;
    float px = pd[pb], py = pd[pb + 1], pz = pd[pb + 2];
    float d0 = 3.4e38f, d1 = 3.4e38f, d2 = 3.4e38f;
    int i0 = -1, i1 = -1, i2 = -1;
    for (int j = sub; j < N2; j += 8) {
        float dx = px - sp[j * 3], dy = py - sp[j * 3 + 1], dz = pz - sp[j * 3 + 2];
        float d = dx * dx + dy * dy + dz * dz;
        if (d < d2) {
            if (d < d0) { d2 = d1; i2 = i1; d1 = d0; i1 = i0; d0 = d; i0 = j; }
            else if (d < d1) { d2 = d1; i2 = i1; d1 = d; i1 = j; }
            else { d2 = d; i2 = j; }
        }
    }
#pragma unroll
    for (int m = 1; m < 8; m <<= 1) {
        float e0 = __shfl_xor(d0, m), e1 = __shfl_xor(d1, m), e2 = __shfl_xor(d2, m);
        int j0 = __shfl_xor(i0, m), j1 = __shfl_xor(i1, m), j2 = __shfl_xor(i2, m);
        if (KLESS(e0, j0, d2, i2)) {
            if (KLESS(e0, j0, d0, i0)) { d2 = d1; i2 = i1; d1 = d0; i1 = i0; d0 = e0; i0 = j0; }
            else if (KLESS(e0, j0, d1, i1)) { d2 = d1; i2 = i1; d1 = e0; i1 = j0; }
            else { d2 = e0; i2 = j0; }
        }
        if (KLESS(e1, j1, d2, i2)) {
            if (KLESS(e1, j1, d0, i0)) { d2 = d1; i2 = i1; d1 = d0; i1 = i0; d0 = e1; i0 = j1; }
            else if (KLESS(e1, j1, d1, i1)) { d2 = d1; i2 = i1; d1 = e1; i1 = j1; }
            else { d2 = e1; i2 = j1; }
        }
        if (KLESS(e2, j2, d2, i2)) {
            if (KLESS(e2, j2, d0, i0)) { d2 = d1; i2 = i1; d1 = d0; i1 = i0; d0 = e2; i0 = j2; }
            else if (KLESS(e2, j2, d1, i1)) { d2 = d1; i2 = i1; d1 = e2; i1 = j2; }
            else { d2 = e2; i2 = j2; }
        }
    }
    if (sub == 0) {
        float w0 = 1.f / (d0 + 1e-8f), w1 = 1.f / (d1 + 1e-8f), w2 = 1.f / (d2 + 1e-8f);
        float s = 1.f / (w0 + w1 + w2);
        size_t o = ((size_t)b * N1 + n) * 3;
        idx[o] = i0; idx[o + 1] = i1; idx[o + 2] = i2;
        w[o] = w0 * s; w[o + 1] = w1 * s; w[o + 2] = w2 * s;
    }
}

// ---------------- build x (point-major): XS[b][n][c] = skipT | interp(fsT) (+BN affine) ----------------
__global__ __launch_bounds__(256) void build_x(const unsigned short* __restrict__ skipT,
                                               const unsigned short* __restrict__ fsT,
                                               const int* __restrict__ idx,
                                               const float* __restrict__ w,
                                               const float* __restrict__ sc,
                                               const float* __restrict__ sh,
                                               unsigned short* __restrict__ x,
                                               int Cskip, int Ctot, int Csp, int N1, int N2) {
    int cq = Ctot >> 2;
    size_t gid = (size_t)blockIdx.x * 256 + threadIdx.x;
    if (gid >= (size_t)4 * N1 * cq) return;
    int c = (int)(gid % cq) * 4;
    int n = (int)((gid / cq) % N1);
    int b = (int)(gid / ((size_t)cq * N1));
    s16x4 o;
    if (c < Cskip) {
        o = *(const s16x4*)(skipT + ((size_t)b * N1 + n) * Cskip + c);
    } else {
        int c2 = c - Cskip;
        size_t ob = ((size_t)b * N1 + n) * 3;
        int i0 = idx[ob], i1 = idx[ob + 1], i2 = idx[ob + 2];
        float w0 = w[ob], w1 = w[ob + 1], w2 = w[ob + 2];
        const unsigned short* f0 = fsT + ((size_t)b * N2 + i0) * Csp + c2;
        const unsigned short* f1 = fsT + ((size_t)b * N2 + i1) * Csp + c2;
        const unsigned short* f2 = fsT + ((size_t)b * N2 + i2) * Csp + c2;
        s16x4 v0 = *(const s16x4*)f0, v1 = *(const s16x4*)f1, v2 = *(const s16x4*)f2;
#pragma unroll
        for (int j = 0; j < 4; j++) {
            float v = w0 * bf2f((unsigned short)v0[j]) + w1 * bf2f((unsigned short)v1[j]) + w2 * bf2f((unsigned short)v2[j]);
            if (sc) v = v * sc[c2 + j] + sh[c2 + j];
            o[j] = (short)f2bf(v);
        }
    }
    *(s16x4*)(x + ((size_t)b * N1 + n) * Ctot + c) = o;
}

// ---------------- bf16 MFMA GEMM: OutT[b][n][m] = sum_k XT[b][n][k] * W[m][k] ----------------
// XT (B,N,K) bf16 (optional per-k affine), W (M,K) fp32, OutT (B,N,M) bf16.
// Epilogue: per-block per-channel partial sum/sumsq -> ps[blin*256 + ml*2 + {0,1}]
__global__ __launch_bounds__(256) void gemm_tn(const unsigned short* __restrict__ XT,
                                               const float* __restrict__ W,
                                               unsigned short* __restrict__ OutT,
                                               const float* __restrict__ sc,
                                               const float* __restrict__ sh,
                                               float* __restrict__ ps,
                                               int N, int K, int M) {
    __shared__ unsigned short As[128 * 40];
    __shared__ unsigned short Bs[128 * 40];
    __shared__ float sred[4][64][2];
    int tid = threadIdx.x;
    int lane = tid & 63, wid = tid >> 6;
    int wn = wid & 1, wm = wid >> 1;
    int bx = blockIdx.x, by = blockIdx.y, bz = blockIdx.z;
    const unsigned short* Xb = XT + (size_t)bz * N * K + (size_t)bx * 128 * K;
    const float* Wb = W + (size_t)by * 128 * K;
    f32x4 acc[4][4];
#pragma unroll
    for (int i = 0; i < 4; i++)
#pragma unroll
        for (int j = 0; j < 4; j++) acc[i][j] = (f32x4)0.f;

    for (int k0 = 0; k0 < K; k0 += 32) {
        __syncthreads();
#pragma unroll
        for (int it = 0; it < 2; it++) {
            int e = tid * 8 + it * 2048;
            int row = e >> 5, k = e & 31;
            s16x8 v = *(const s16x8*)(Xb + (size_t)row * K + k0 + k);
            if (sc) {
#pragma unroll
                for (int j = 0; j < 8; j++) {
                    float f = bf2f((unsigned short)v[j]);
                    f = fmaf(f, sc[k0 + k + j], sh[k0 + k + j]);
                    v[j] = (short)f2bf(f);
                }
            }
            *(s16x8*)&As[row * 40 + k] = v;
        }
#pragma unroll
        for (int it = 0; it < 4; it++) {
            int e = tid * 4 + it * 1024;
            int row = e >> 5, k = e & 31;
            float4 f = *(const float4*)(Wb + (size_t)row * K + k0 + k);
            s16x4 v = { (short)f2bf(f.x), (short)f2bf(f.y), (short)f2bf(f.z), (short)f2bf(f.w) };
            *(s16x4*)&Bs[row * 40 + k] = v;
        }
        __syncthreads();
        int koff = (lane >> 4) * 8;
        int rA = wn * 64 + (lane & 15);
        int rB = wm * 64 + (lane & 15);
        s16x8 afr[4], bfr[4];
#pragma unroll
        for (int i = 0; i < 4; i++) afr[i] = *(const s16x8*)&As[(rA + i * 16) * 40 + koff];
#pragma unroll
        for (int j = 0; j < 4; j++) bfr[j] = *(const s16x8*)&Bs[(rB + j * 16) * 40 + koff];
#pragma unroll
        for (int i = 0; i < 4; i++)
#pragma unroll
            for (int j = 0; j < 4; j++)
                acc[i][j] = __builtin_amdgcn_mfma_f32_16x16x32_bf16(afr[i], bfr[j], acc[i][j], 0, 0, 0);
    }

    // epilogue: store bf16 output + per-channel partial stats
    int q4 = lane >> 4;
    unsigned short* Ob = OutT + (size_t)bz * N * M + (size_t)bx * 128 * M + by * 128;
    float s[4] = {0.f, 0.f, 0.f, 0.f}, q[4] = {0.f, 0.f, 0.f, 0.f};
#pragma unroll
    for (int i = 0; i < 4; i++) {
#pragma unroll
        for (int j = 0; j < 4; j++) {
            int mcol = wm * 64 + j * 16 + (lane & 15);
#pragma unroll
            for (int r = 0; r < 4; r++) {
                float v = acc[i][j][r];
                s[j] += v; q[j] += v * v;
                int n = wn * 64 + i * 16 + q4 * 4 + r;
                Ob[(size_t)n * M + mcol] = f2bf(v);
            }
        }
    }
#pragma unroll
    for (int j = 0; j < 4; j++) {
        s[j] += __shfl_xor(s[j], 16); s[j] += __shfl_xor(s[j], 32);
        q[j] += __shfl_xor(q[j], 16); q[j] += __shfl_xor(q[j], 32);
    }
    if (lane < 16) {
#pragma unroll
        for (int j = 0; j < 4; j++) {
            sred[wid][j * 16 + lane][0] = s[j];
            sred[wid][j * 16 + lane][1] = q[j];
        }
    }
    __syncthreads();
    if (tid < 128) {
        int wmm = tid >> 6, off = tid & 63;
        float ss = sred[wmm * 2][off][0] + sred[wmm * 2 + 1][off][0];
        float qq = sred[wmm * 2][off][1] + sred[wmm * 2 + 1][off][1];
        size_t blin = ((size_t)bz * gridDim.y + by) * gridDim.x + bx;
        ps[blin * 256 + tid * 2] = ss;
        ps[blin * 256 + tid * 2 + 1] = qq;
    }
}

// ---------------- finalize BN: reduce partials -> scale/shift ----------------
__global__ __launch_bounds__(256) void bn_finalize(const float* __restrict__ ps,
                                                   const float* __restrict__ g,
                                                   const float* __restrict__ bb,
                                                   float* __restrict__ sc,
                                                   float* __restrict__ sh,
                                                   int gx, int gz, int M, int Npts) {
    int m = blockIdx.x * 256 + threadIdx.x;
    if (m >= M) return;
    int by = m >> 7, ml = m & 127;
    int gy = M >> 7;
    float s = 0.f, q = 0.f;
    for (int bz = 0; bz < gz; bz++)
        for (int bx = 0; bx < gx; bx++) {
            size_t blin = ((size_t)bz * gy + by) * gx + bx;
            s += ps[blin * 256 + ml * 2];
            q += ps[blin * 256 + ml * 2 + 1];
        }
    float inv = 1.f / (float)Npts;
    float mean = s * inv;
    float var = fmaxf(q * inv - mean * mean, 0.f);
    float scale = g[m] * rsqrtf(var + BN_EPS);
    sc[m] = scale;
    sh[m] = bb[m] - mean * scale;
}

// ---------------- final: (B,N,M) bf16 -> (B,M,N) fp32 with BN affine ----------------
__global__ __launch_bounds__(256) void out_bn_tr(const unsigned short* __restrict__ in,
                                                 float* __restrict__ out,
                                                 const float* __restrict__ sc,
                                                 const float* __restrict__ sh,
                                                 int M, int N) {
    __shared__ float t[32][33];
    int b = blockIdx.z;
    int n0 = blockIdx.x * 32, m0 = blockIdx.y * 32;
    int j = threadIdx.x & 31, ii = threadIdx.x >> 5;
#pragma unroll
    for (int i = ii; i < 32; i += 8)
        t[i][j] = bf2f(in[((size_t)b * N + n0 + i) * M + m0 + j]);
    __syncthreads();
    int i2 = threadIdx.x & 31, j2b = threadIdx.x >> 5;
#pragma unroll
    for (int j2 = j2b; j2 < 32; j2 += 8)
        out[((size_t)b * M + m0 + j2) * N + n0 + i2] = t[i2][j2] * sc[m0 + j2] + sh[m0 + j2];
}

extern "C" void kernel_launch(void* const* d_in, const int* in_sizes, int n_in,
                              void* d_out, int out_size, void* d_ws, size_t ws_size,
                              hipStream_t stream) {
    const float* p1 = (const float*)d_in[1];
    const float* p2 = (const float*)d_in[2];
    const float* p3 = (const float*)d_in[3];
    const float* p4 = (const float*)d_in[4];
    const float* f1 = (const float*)d_in[5];
    const float* f2 = (const float*)d_in[6];
    const float* f3 = (const float*)d_in[7];
    const float* f4 = (const float*)d_in[8];
    const int* cls = (const int*)d_in[9];
    const float* Wc1 = (const float*)d_in[10];
    const float* gc  = (const float*)d_in[11];
    const float* bc  = (const float*)d_in[12];
    const float* Wc2 = (const float*)d_in[13];
    const float* Ws2a = (const float*)d_in[14];
    const float* gs2a = (const float*)d_in[15];
    const float* bs2a = (const float*)d_in[16];
    const float* Ws2b = (const float*)d_in[17];
    const float* gs2b = (const float*)d_in[18];
    const float* bs2b = (const float*)d_in[19];
    const float* Ws1a = (const float*)d_in[20];
    const float* gs1a = (const float*)d_in[21];
    const float* bs1a = (const float*)d_in[22];
    const float* Ws1b = (const float*)d_in[23];
    const float* gs1b = (const float*)d_in[24];
    const float* bs1b = (const float*)d_in[25];
    const float* Ws0a = (const float*)d_in[26];
    const float* gs0a = (const float*)d_in[27];
    const float* bs0a = (const float*)d_in[28];
    const float* Ws0b = (const float*)d_in[29];
    const float* gs0b = (const float*)d_in[30];
    const float* bs0b = (const float*)d_in[31];

    // workspace layout (bytes)
    char* ws = (char*)d_ws;
    size_t off = 0;
    auto alloc = [&](size_t bytes) { char* p = ws + off; off += (bytes + 255) & ~(size_t)255; return p; };
    unsigned short* F4T = (unsigned short*)alloc((size_t)4 * 128 * 1024 * 2);
    unsigned short* F3T = (unsigned short*)alloc((size_t)4 * 512 * 512 * 2);
    unsigned short* F2T = (unsigned short*)alloc((size_t)4 * 2048 * 256 * 2);
    unsigned short* F1T = (unsigned short*)alloc((size_t)4 * 8192 * 128 * 2);
    unsigned short* XS  = (unsigned short*)alloc((size_t)4 * 8192 * 384 * 2);
    unsigned short* YA  = (unsigned short*)alloc((size_t)4 * 8192 * 128 * 2); // also fits s2(512x512), s1(2048x256)
    unsigned short* FN2 = (unsigned short*)alloc((size_t)4 * 512 * 512 * 2);
    unsigned short* FN1 = (unsigned short*)alloc((size_t)4 * 2048 * 256 * 2);
    int*   IDX = (int*)alloc((size_t)4 * 8192 * 3 * 4);
    float* WGT = (float*)alloc((size_t)4 * 8192 * 3 * 4);
    float* CLSV = (float*)alloc(4 * 128 * 4);
    float* PS = (float*)alloc((size_t)256 * 256 * 4);
    float* SC2a = (float*)alloc(512 * 4); float* SH2a = (float*)alloc(512 * 4);
    float* SC2b = (float*)alloc(512 * 4); float* SH2b = (float*)alloc(512 * 4);
    float* SC1a = (float*)alloc(512 * 4); float* SH1a = (float*)alloc(512 * 4);
    float* SC1b = (float*)alloc(512 * 4); float* SH1b = (float*)alloc(512 * 4);
    float* SC0a = (float*)alloc(512 * 4); float* SH0a = (float*)alloc(512 * 4);
    float* SC0b = (float*)alloc(512 * 4); float* SH0b = (float*)alloc(512 * 4);
    float* OUT = (float*)d_out;

    // class embedding, then transposes to point-major bf16
    cls_kernel<<<1, 512, 0, stream>>>(cls, Wc1, gc, bc, Wc2, CLSV);
    transpose_cp<<<dim3(128 / 32, 1024 / 32, 4), 256, 0, stream>>>(f4, F4T, nullptr, 1024, 128);
    transpose_cp<<<dim3(512 / 32, 512 / 32, 4), 256, 0, stream>>>(f3, F3T, nullptr, 512, 512);
    transpose_cp<<<dim3(2048 / 32, 256 / 32, 4), 256, 0, stream>>>(f2, F2T, nullptr, 256, 2048);
    transpose_cp<<<dim3(8192 / 32, 128 / 32, 4), 256, 0, stream>>>(f1, F1T, CLSV, 128, 8192);

    // ---- stage s2: 512 pts <- 128 pts, K=1536 -> 512 -> 512
    knn_kernel<<<dim3(512 / 32, 4), 256, 0, stream>>>(p3, p4, 512, 128, IDX, WGT);
    build_x<<<(int)(((size_t)4 * 512 * (1536 / 4) + 255) / 256), 256, 0, stream>>>(
        F3T, F4T, IDX, WGT, nullptr, nullptr, XS, 512, 1536, 1024, 512, 128);
    gemm_tn<<<dim3(4, 4, 4), 256, 0, stream>>>(XS, Ws2a, YA, nullptr, nullptr, PS, 512, 1536, 512);
    bn_finalize<<<2, 256, 0, stream>>>(PS, gs2a, bs2a, SC2a, SH2a, 4, 4, 512, 4 * 512);
    gemm_tn<<<dim3(4, 4, 4), 256, 0, stream>>>(YA, Ws2b, FN2, SC2a, SH2a, PS, 512, 512, 512);
    bn_finalize<<<2, 256, 0, stream>>>(PS, gs2b, bs2b, SC2b, SH2b, 4, 4, 512, 4 * 512);

    // ---- stage s1: 2048 pts <- 512 pts, K=768 -> 256 -> 256
    knn_kernel<<<dim3(2048 / 32, 4), 256, 0, stream>>>(p2, p3, 2048, 512, IDX, WGT);
    build_x<<<(int)(((size_t)4 * 2048 * (768 / 4) + 255) / 256), 256, 0, stream>>>(
        F2T, FN2, IDX, WGT, SC2b, SH2b, XS, 256, 768, 512, 2048, 512);
    gemm_tn<<<dim3(16, 2, 4), 256, 0, stream>>>(XS, Ws1a, YA, nullptr, nullptr, PS, 2048, 768, 256);
    bn_finalize<<<1, 256, 0, stream>>>(PS, gs1a, bs1a, SC1a, SH1a, 16, 4, 256, 4 * 2048);
    gemm_tn<<<dim3(16, 2, 4), 256, 0, stream>>>(YA, Ws1b, FN1, SC1a, SH1a, PS, 2048, 256, 256);
    bn_finalize<<<1, 256, 0, stream>>>(PS, gs1b, bs1b, SC1b, SH1b, 16, 4, 256, 4 * 2048);

    // ---- stage s0: 8192 pts <- 2048 pts, K=384 -> 128 -> 128
    knn_kernel<<<dim3(8192 / 32, 4), 256, 0, stream>>>(p1, p2, 8192, 2048, IDX, WGT);
    build_x<<<(int)(((size_t)4 * 8192 * (384 / 4) + 255) / 256), 256, 0, stream>>>(
        F1T, FN1, IDX, WGT, SC1b, SH1b, XS, 128, 384, 256, 8192, 2048);
    gemm_tn<<<dim3(64, 1, 4), 256, 0, stream>>>(XS, Ws0a, YA, nullptr, nullptr, PS, 8192, 384, 128);
    bn_finalize<<<1, 256, 0, stream>>>(PS, gs0a, bs0a, SC0a, SH0a, 64, 4, 128, 4 * 8192);
    gemm_tn<<<dim3(64, 1, 4), 256, 0, stream>>>(YA, Ws0b, XS, SC0a, SH0a, PS, 8192, 128, 128);
    bn_finalize<<<1, 256, 0, stream>>>(PS, gs0b, bs0b, SC0b, SH0b, 64, 4, 128, 4 * 8192);

    // final BN + transpose to (B,128,8192) fp32
    out_bn_tr<<<dim3(8192 / 32, 128 / 32, 4), 256, 0, stream>>>(XS, OUT, SC0b, SH0b, 128, 8192);
}

// Round 3
// 395.082 us; speedup vs baseline: 3.1071x; 1.2014x over previous
//
#include <hip/hip_runtime.h>
#include <math.h>

#define BN_EPS 1e-5f

typedef float f32x4 __attribute__((ext_vector_type(4)));
typedef short s16x8 __attribute__((ext_vector_type(8)));
typedef short s16x4 __attribute__((ext_vector_type(4)));

__device__ __forceinline__ unsigned short f2bf(float f) {
    unsigned u = __builtin_bit_cast(unsigned, f);
    u = u + 0x7FFFu + ((u >> 16) & 1u);
    return (unsigned short)(u >> 16);
}
__device__ __forceinline__ float bf2f(unsigned short s) {
    unsigned u = ((unsigned)s) << 16;
    return __builtin_bit_cast(float, u);
}

// ---------------- class-embedding MLP: 16 -> 64 (BN+GELU) -> 128 ----------------
__global__ __launch_bounds__(512) void cls_kernel(const int* __restrict__ lbl,
                                                  const float* __restrict__ Wc1,
                                                  const float* __restrict__ gc,
                                                  const float* __restrict__ bc,
                                                  const float* __restrict__ Wc2,
                                                  float* __restrict__ cls_vec) {
    __shared__ float h[4 * 64];
    __shared__ float act[4 * 64];
    int tid = threadIdx.x;
    if (tid < 256) {
        int b = tid >> 6, c = tid & 63;
        h[b * 64 + c] = Wc1[c * 16 + lbl[b]];
    }
    __syncthreads();
    if (tid < 64) {
        int c = tid;
        float m = 0.f;
        for (int b = 0; b < 4; b++) m += h[b * 64 + c];
        m *= 0.25f;
        float v = 0.f;
        for (int b = 0; b < 4; b++) { float d = h[b * 64 + c] - m; v += d * d; }
        v *= 0.25f;
        float sc = gc[c] * rsqrtf(v + BN_EPS);
        float sh = bc[c] - m * sc;
        for (int b = 0; b < 4; b++) {
            float x = h[b * 64 + c] * sc + sh;
            act[b * 64 + c] = 0.5f * x * (1.f + erff(x * 0.70710678118654752f));
        }
    }
    __syncthreads();
    int b = tid >> 7, o = tid & 127;
    float s = 0.f;
    for (int c = 0; c < 64; c++) s += Wc2[o * 64 + c] * act[b * 64 + c];
    cls_vec[b * 128 + o] = s;
}

// ---------------- transpose (B,C,N) fp32 -> (B,N,C) bf16, optional per-channel add ----------------
__global__ __launch_bounds__(256) void transpose_cp(const float* __restrict__ in,
                                                    unsigned short* __restrict__ out,
                                                    const float* __restrict__ addv,
                                                    int C, int N) {
    __shared__ float t[32][33];
    int b = blockIdx.z;
    int n0 = blockIdx.x * 32, c0 = blockIdx.y * 32;
    int i = threadIdx.x & 31, jj = threadIdx.x >> 5;
#pragma unroll
    for (int j = jj; j < 32; j += 8) {
        float v = in[((size_t)b * C + c0 + j) * N + n0 + i];
        if (addv) v += addv[b * C + c0 + j];
        t[j][i] = v;
    }
    __syncthreads();
    int j2 = threadIdx.x & 31, i2b = threadIdx.x >> 5;
#pragma unroll
    for (int i2 = i2b; i2 < 32; i2 += 8)
        out[((size_t)b * N + n0 + i2) * C + c0 + j2] = f2bf(t[j2][i2]);
}

// ---------------- 3-NN: 8 lanes per dense point, butterfly merge ----------------
#define KLESS(d, i, dd, ii) ((d) < (dd) || ((d) == (dd) && (i) < (ii)))
__global__ __launch_bounds__(256) void knn_kernel(const float* __restrict__ pd,
                                                  const float* __restrict__ ps,
                                                  int N1, int N2,
                                                  int* __restrict__ idx,
                                                  float* __restrict__ w) {
    __shared__ float sp[2048 * 3];
    int b = blockIdx.y;
    int tid = threadIdx.x;
    for (int t = tid; t < N2 * 3; t += 256) sp[t] = ps[(size_t)b * N2 * 3 + t];
    __syncthreads();
    int sub = tid & 7;
    int n = blockIdx.x * 32 + (tid >> 3);
    size_t pb = ((size_t)b * N1 + n) * 3;
    float px = pd[pb], py = pd[pb + 1], pz = pd[pb + 2];
    float d0 = 3.4e38f, d1 = 3.4e38f, d2 = 3.4e38f;
    int i0 = -1, i1 = -1, i2 = -1;
    for (int j = sub; j < N2; j += 8) {
        float dx = px - sp[j * 3], dy = py - sp[j * 3 + 1], dz = pz - sp[j * 3 + 2];
        float d = dx * dx + dy * dy + dz * dz;
        if (d < d2) {
            if (d < d0) { d2 = d1; i2 = i1; d1 = d0; i1 = i0; d0 = d; i0 = j; }
            else if (d < d1) { d2 = d1; i2 = i1; d1 = d; i1 = j; }
            else { d2 = d; i2 = j; }
        }
    }
#pragma unroll
    for (int m = 1; m < 8; m <<= 1) {
        float e0 = __shfl_xor(d0, m), e1 = __shfl_xor(d1, m), e2 = __shfl_xor(d2, m);
        int j0 = __shfl_xor(i0, m), j1 = __shfl_xor(i1, m), j2 = __shfl_xor(i2, m);
        if (KLESS(e0, j0, d2, i2)) {
            if (KLESS(e0, j0, d0, i0)) { d2 = d1; i2 = i1; d1 = d0; i1 = i0; d0 = e0; i0 = j0; }
            else if (KLESS(e0, j0, d1, i1)) { d2 = d1; i2 = i1; d1 = e0; i1 = j0; }
            else { d2 = e0; i2 = j0; }
        }
        if (KLESS(e1, j1, d2, i2)) {
            if (KLESS(e1, j1, d0, i0)) { d2 = d1; i2 = i1; d1 = d0; i1 = i0; d0 = e1; i0 = j1; }
            else if (KLESS(e1, j1, d1, i1)) { d2 = d1; i2 = i1; d1 = e1; i1 = j1; }
            else { d2 = e1; i2 = j1; }
        }
        if (KLESS(e2, j2, d2, i2)) {
            if (KLESS(e2, j2, d0, i0)) { d2 = d1; i2 = i1; d1 = d0; i1 = i0; d0 = e2; i0 = j2; }
            else if (KLESS(e2, j2, d1, i1)) { d2 = d1; i2 = i1; d1 = e2; i1 = j2; }
            else { d2 = e2; i2 = j2; }
        }
    }
    if (sub == 0) {
        float w0 = 1.f / (d0 + 1e-8f), w1 = 1.f / (d1 + 1e-8f), w2 = 1.f / (d2 + 1e-8f);
        float s = 1.f / (w0 + w1 + w2);
        size_t o = ((size_t)b * N1 + n) * 3;
        idx[o] = i0; idx[o + 1] = i1; idx[o + 2] = i2;
        w[o] = w0 * s; w[o + 1] = w1 * s; w[o + 2] = w2 * s;
    }
}

// ---------------- build x (point-major): XS[b][n][c] = skipT | interp(fsT) (+BN affine) ----------------
__global__ __launch_bounds__(256) void build_x(const unsigned short* __restrict__ skipT,
                                               const unsigned short* __restrict__ fsT,
                                               const int* __restrict__ idx,
                                               const float* __restrict__ w,
                                               const float* __restrict__ sc,
                                               const float* __restrict__ sh,
                                               unsigned short* __restrict__ x,
                                               int Cskip, int Ctot, int Csp, int N1, int N2) {
    int cq = Ctot >> 2;
    size_t gid = (size_t)blockIdx.x * 256 + threadIdx.x;
    if (gid >= (size_t)4 * N1 * cq) return;
    int c = (int)(gid % cq) * 4;
    int n = (int)((gid / cq) % N1);
    int b = (int)(gid / ((size_t)cq * N1));
    s16x4 o;
    if (c < Cskip) {
        o = *(const s16x4*)(skipT + ((size_t)b * N1 + n) * Cskip + c);
    } else {
        int c2 = c - Cskip;
        size_t ob = ((size_t)b * N1 + n) * 3;
        int i0 = idx[ob], i1 = idx[ob + 1], i2 = idx[ob + 2];
        float w0 = w[ob], w1 = w[ob + 1], w2 = w[ob + 2];
        const unsigned short* f0 = fsT + ((size_t)b * N2 + i0) * Csp + c2;
        const unsigned short* f1 = fsT + ((size_t)b * N2 + i1) * Csp + c2;
        const unsigned short* f2 = fsT + ((size_t)b * N2 + i2) * Csp + c2;
        s16x4 v0 = *(const s16x4*)f0, v1 = *(const s16x4*)f1, v2 = *(const s16x4*)f2;
#pragma unroll
        for (int j = 0; j < 4; j++) {
            float v = w0 * bf2f((unsigned short)v0[j]) + w1 * bf2f((unsigned short)v1[j]) + w2 * bf2f((unsigned short)v2[j]);
            if (sc) v = v * sc[c2 + j] + sh[c2 + j];
            o[j] = (short)f2bf(v);
        }
    }
    *(s16x4*)(x + ((size_t)b * N1 + n) * Ctot + c) = o;
}

// ---------------- bf16 MFMA GEMM: OutT[b][n][m] = sum_k XT[b][n][k] * W[m][k] ----------------
// Tile: 64 (N) x 128 (M), 4 waves in 2x2. XT (B,N,K) bf16 (opt per-k affine), W (M,K) fp32, OutT (B,N,M) bf16.
// Epilogue: per-block per-channel partial sum/sumsq -> ps[blin*256 + m*2 + {0,1}], m<128.
__global__ __launch_bounds__(256) void gemm_tn(const unsigned short* __restrict__ XT,
                                               const float* __restrict__ W,
                                               unsigned short* __restrict__ OutT,
                                               const float* __restrict__ sc,
                                               const float* __restrict__ sh,
                                               float* __restrict__ ps,
                                               int N, int K, int M) {
    __shared__ unsigned short As[64 * 40];
    __shared__ unsigned short Bs[128 * 40];
    __shared__ float sred[4][64][2];
    int tid = threadIdx.x;
    int lane = tid & 63, wid = tid >> 6;
    int wn = wid & 1, wm = wid >> 1;
    int bx = blockIdx.x, by = blockIdx.y, bz = blockIdx.z;
    const unsigned short* Xb = XT + (size_t)bz * N * K + (size_t)bx * 64 * K;
    const float* Wb = W + (size_t)by * 128 * K;
    f32x4 acc[2][4];
#pragma unroll
    for (int i = 0; i < 2; i++)
#pragma unroll
        for (int j = 0; j < 4; j++) acc[i][j] = (f32x4)0.f;

    for (int k0 = 0; k0 < K; k0 += 32) {
        __syncthreads();
        {
            int e = tid * 8;
            int row = e >> 5, k = e & 31;
            s16x8 v = *(const s16x8*)(Xb + (size_t)row * K + k0 + k);
            if (sc) {
#pragma unroll
                for (int j = 0; j < 8; j++) {
                    float f = bf2f((unsigned short)v[j]);
                    f = fmaf(f, sc[k0 + k + j], sh[k0 + k + j]);
                    v[j] = (short)f2bf(f);
                }
            }
            *(s16x8*)&As[row * 40 + k] = v;
        }
#pragma unroll
        for (int it = 0; it < 4; it++) {
            int e = tid * 4 + it * 1024;
            int row = e >> 5, k = e & 31;
            float4 f = *(const float4*)(Wb + (size_t)row * K + k0 + k);
            s16x4 v = { (short)f2bf(f.x), (short)f2bf(f.y), (short)f2bf(f.z), (short)f2bf(f.w) };
            *(s16x4*)&Bs[row * 40 + k] = v;
        }
        __syncthreads();
        int koff = (lane >> 4) * 8;
        s16x8 afr[2], bfr[4];
#pragma unroll
        for (int i = 0; i < 2; i++) afr[i] = *(const s16x8*)&As[(wn * 32 + i * 16 + (lane & 15)) * 40 + koff];
#pragma unroll
        for (int j = 0; j < 4; j++) bfr[j] = *(const s16x8*)&Bs[(wm * 64 + j * 16 + (lane & 15)) * 40 + koff];
#pragma unroll
        for (int i = 0; i < 2; i++)
#pragma unroll
            for (int j = 0; j < 4; j++)
                acc[i][j] = __builtin_amdgcn_mfma_f32_16x16x32_bf16(afr[i], bfr[j], acc[i][j], 0, 0, 0);
    }

    int q4 = lane >> 4;
    unsigned short* Ob = OutT + (size_t)bz * N * M + (size_t)bx * 64 * M + by * 128;
    float s[4] = {0.f, 0.f, 0.f, 0.f}, q[4] = {0.f, 0.f, 0.f, 0.f};
#pragma unroll
    for (int i = 0; i < 2; i++) {
#pragma unroll
        for (int j = 0; j < 4; j++) {
            int mcol = wm * 64 + j * 16 + (lane & 15);
#pragma unroll
            for (int r = 0; r < 4; r++) {
                float v = acc[i][j][r];
                s[j] += v; q[j] += v * v;
                int n = wn * 32 + i * 16 + q4 * 4 + r;
                Ob[(size_t)n * M + mcol] = f2bf(v);
            }
        }
    }
#pragma unroll
    for (int j = 0; j < 4; j++) {
        s[j] += __shfl_xor(s[j], 16); s[j] += __shfl_xor(s[j], 32);
        q[j] += __shfl_xor(q[j], 16); q[j] += __shfl_xor(q[j], 32);
    }
    if (lane < 16) {
#pragma unroll
        for (int j = 0; j < 4; j++) {
            sred[wid][j * 16 + lane][0] = s[j];
            sred[wid][j * 16 + lane][1] = q[j];
        }
    }
    __syncthreads();
    if (tid < 128) {
        int mb = tid >> 6, off = tid & 63;
        float ss = sred[mb * 2][off][0] + sred[mb * 2 + 1][off][0];
        float qq = sred[mb * 2][off][1] + sred[mb * 2 + 1][off][1];
        size_t blin = ((size_t)bz * gridDim.y + by) * gridDim.x + bx;
        ps[blin * 256 + tid * 2] = ss;
        ps[blin * 256 + tid * 2 + 1] = qq;
    }
}

// ---------------- finalize BN: one block per channel, parallel partial reduce ----------------
__global__ __launch_bounds__(256) void bn_finalize(const float* __restrict__ ps,
                                                   const float* __restrict__ g,
                                                   const float* __restrict__ bb,
                                                   float* __restrict__ sc,
                                                   float* __restrict__ sh,
                                                   int gx, int gy, int Npts) {
    int m = blockIdx.x;
    int by = m >> 7, ml = m & 127;
    int P = 4 * gx;
    float s = 0.f, q = 0.f;
    for (int t = threadIdx.x; t < P; t += 256) {
        int bz = t / gx, bx = t - bz * gx;
        size_t blin = ((size_t)bz * gy + by) * gx + bx;
        s += ps[blin * 256 + ml * 2];
        q += ps[blin * 256 + ml * 2 + 1];
    }
    __shared__ float ls[256], lq[256];
    ls[threadIdx.x] = s; lq[threadIdx.x] = q;
    __syncthreads();
    for (int o = 128; o > 0; o >>= 1) {
        if (threadIdx.x < o) { ls[threadIdx.x] += ls[threadIdx.x + o]; lq[threadIdx.x] += lq[threadIdx.x + o]; }
        __syncthreads();
    }
    if (threadIdx.x == 0) {
        float inv = 1.f / (float)Npts;
        float mean = ls[0] * inv;
        float var = fmaxf(lq[0] * inv - mean * mean, 0.f);
        float scale = g[m] * rsqrtf(var + BN_EPS);
        sc[m] = scale;
        sh[m] = bb[m] - mean * scale;
    }
}

// ---------------- final: (B,N,M) bf16 -> (B,M,N) fp32 with BN affine ----------------
__global__ __launch_bounds__(256) void out_bn_tr(const unsigned short* __restrict__ in,
                                                 float* __restrict__ out,
                                                 const float* __restrict__ sc,
                                                 const float* __restrict__ sh,
                                                 int M, int N) {
    __shared__ float t[32][33];
    int b = blockIdx.z;
    int n0 = blockIdx.x * 32, m0 = blockIdx.y * 32;
    int j = threadIdx.x & 31, ii = threadIdx.x >> 5;
#pragma unroll
    for (int i = ii; i < 32; i += 8)
        t[i][j] = bf2f(in[((size_t)b * N + n0 + i) * M + m0 + j]);
    __syncthreads();
    int i2 = threadIdx.x & 31, j2b = threadIdx.x >> 5;
#pragma unroll
    for (int j2 = j2b; j2 < 32; j2 += 8)
        out[((size_t)b * M + m0 + j2) * N + n0 + i2] = t[i2][j2] * sc[m0 + j2] + sh[m0 + j2];
}

extern "C" void kernel_launch(void* const* d_in, const int* in_sizes, int n_in,
                              void* d_out, int out_size, void* d_ws, size_t ws_size,
                              hipStream_t stream) {
    const float* p1 = (const float*)d_in[1];
    const float* p2 = (const float*)d_in[2];
    const float* p3 = (const float*)d_in[3];
    const float* p4 = (const float*)d_in[4];
    const float* f1 = (const float*)d_in[5];
    const float* f2 = (const float*)d_in[6];
    const float* f3 = (const float*)d_in[7];
    const float* f4 = (const float*)d_in[8];
    const int* cls = (const int*)d_in[9];
    const float* Wc1 = (const float*)d_in[10];
    const float* gc  = (const float*)d_in[11];
    const float* bc  = (const float*)d_in[12];
    const float* Wc2 = (const float*)d_in[13];
    const float* Ws2a = (const float*)d_in[14];
    const float* gs2a = (const float*)d_in[15];
    const float* bs2a = (const float*)d_in[16];
    const float* Ws2b = (const float*)d_in[17];
    const float* gs2b = (const float*)d_in[18];
    const float* bs2b = (const float*)d_in[19];
    const float* Ws1a = (const float*)d_in[20];
    const float* gs1a = (const float*)d_in[21];
    const float* bs1a = (const float*)d_in[22];
    const float* Ws1b = (const float*)d_in[23];
    const float* gs1b = (const float*)d_in[24];
    const float* bs1b = (const float*)d_in[25];
    const float* Ws0a = (const float*)d_in[26];
    const float* gs0a = (const float*)d_in[27];
    const float* bs0a = (const float*)d_in[28];
    const float* Ws0b = (const float*)d_in[29];
    const float* gs0b = (const float*)d_in[30];
    const float* bs0b = (const float*)d_in[31];

    char* ws = (char*)d_ws;
    size_t off = 0;
    auto alloc = [&](size_t bytes) { char* p = ws + off; off += (bytes + 255) & ~(size_t)255; return p; };
    unsigned short* F4T = (unsigned short*)alloc((size_t)4 * 128 * 1024 * 2);
    unsigned short* F3T = (unsigned short*)alloc((size_t)4 * 512 * 512 * 2);
    unsigned short* F2T = (unsigned short*)alloc((size_t)4 * 2048 * 256 * 2);
    unsigned short* F1T = (unsigned short*)alloc((size_t)4 * 8192 * 128 * 2);
    unsigned short* XS  = (unsigned short*)alloc((size_t)4 * 8192 * 384 * 2);
    unsigned short* YA  = (unsigned short*)alloc((size_t)4 * 8192 * 128 * 2);
    unsigned short* FN2 = (unsigned short*)alloc((size_t)4 * 512 * 512 * 2);
    unsigned short* FN1 = (unsigned short*)alloc((size_t)4 * 2048 * 256 * 2);
    int*   IDX = (int*)alloc((size_t)4 * 8192 * 3 * 4);
    float* WGT = (float*)alloc((size_t)4 * 8192 * 3 * 4);
    float* CLSV = (float*)alloc(4 * 128 * 4);
    float* PS = (float*)alloc((size_t)512 * 256 * 4);
    float* SC2a = (float*)alloc(512 * 4); float* SH2a = (float*)alloc(512 * 4);
    float* SC2b = (float*)alloc(512 * 4); float* SH2b = (float*)alloc(512 * 4);
    float* SC1a = (float*)alloc(512 * 4); float* SH1a = (float*)alloc(512 * 4);
    float* SC1b = (float*)alloc(512 * 4); float* SH1b = (float*)alloc(512 * 4);
    float* SC0a = (float*)alloc(512 * 4); float* SH0a = (float*)alloc(512 * 4);
    float* SC0b = (float*)alloc(512 * 4); float* SH0b = (float*)alloc(512 * 4);
    float* OUT = (float*)d_out;

    cls_kernel<<<1, 512, 0, stream>>>(cls, Wc1, gc, bc, Wc2, CLSV);
    transpose_cp<<<dim3(128 / 32, 1024 / 32, 4), 256, 0, stream>>>(f4, F4T, nullptr, 1024, 128);
    transpose_cp<<<dim3(512 / 32, 512 / 32, 4), 256, 0, stream>>>(f3, F3T, nullptr, 512, 512);
    transpose_cp<<<dim3(2048 / 32, 256 / 32, 4), 256, 0, stream>>>(f2, F2T, nullptr, 256, 2048);
    transpose_cp<<<dim3(8192 / 32, 128 / 32, 4), 256, 0, stream>>>(f1, F1T, CLSV, 128, 8192);

    // ---- stage s2: 512 pts <- 128 pts, K=1536 -> 512 -> 512
    knn_kernel<<<dim3(512 / 32, 4), 256, 0, stream>>>(p3, p4, 512, 128, IDX, WGT);
    build_x<<<(int)(((size_t)4 * 512 * (1536 / 4) + 255) / 256), 256, 0, stream>>>(
        F3T, F4T, IDX, WGT, nullptr, nullptr, XS, 512, 1536, 1024, 512, 128);
    gemm_tn<<<dim3(8, 4, 4), 256, 0, stream>>>(XS, Ws2a, YA, nullptr, nullptr, PS, 512, 1536, 512);
    bn_finalize<<<512, 256, 0, stream>>>(PS, gs2a, bs2a, SC2a, SH2a, 8, 4, 4 * 512);
    gemm_tn<<<dim3(8, 4, 4), 256, 0, stream>>>(YA, Ws2b, FN2, SC2a, SH2a, PS, 512, 512, 512);
    bn_finalize<<<512, 256, 0, stream>>>(PS, gs2b, bs2b, SC2b, SH2b, 8, 4, 4 * 512);

    // ---- stage s1: 2048 pts <- 512 pts, K=768 -> 256 -> 256
    knn_kernel<<<dim3(2048 / 32, 4), 256, 0, stream>>>(p2, p3, 2048, 512, IDX, WGT);
    build_x<<<(int)(((size_t)4 * 2048 * (768 / 4) + 255) / 256), 256, 0, stream>>>(
        F2T, FN2, IDX, WGT, SC2b, SH2b, XS, 256, 768, 512, 2048, 512);
    gemm_tn<<<dim3(32, 2, 4), 256, 0, stream>>>(XS, Ws1a, YA, nullptr, nullptr, PS, 2048, 768, 256);
    bn_finalize<<<256, 256, 0, stream>>>(PS, gs1a, bs1a, SC1a, SH1a, 32, 2, 4 * 2048);
    gemm_tn<<<dim3(32, 2, 4), 256, 0, stream>>>(YA, Ws1b, FN1, SC1a, SH1a, PS, 2048, 256, 256);
    bn_finalize<<<256, 256, 0, stream>>>(PS, gs1b, bs1b, SC1b, SH1b, 32, 2, 4 * 2048);

    // ---- stage s0: 8192 pts <- 2048 pts, K=384 -> 128 -> 128
    knn_kernel<<<dim3(8192 / 32, 4), 256, 0, stream>>>(p1, p2, 8192, 2048, IDX, WGT);
    build_x<<<(int)(((size_t)4 * 8192 * (384 / 4) + 255) / 256), 256, 0, stream>>>(
        F1T, FN1, IDX, WGT, SC1b, SH1b, XS, 128, 384, 256, 8192, 2048);
    gemm_tn<<<dim3(128, 1, 4), 256, 0, stream>>>(XS, Ws0a, YA, nullptr, nullptr, PS, 8192, 384, 128);
    bn_finalize<<<128, 256, 0, stream>>>(PS, gs0a, bs0a, SC0a, SH0a, 128, 1, 4 * 8192);
    gemm_tn<<<dim3(128, 1, 4), 256, 0, stream>>>(YA, Ws0b, XS, SC0a, SH0a, PS, 8192, 128, 128);
    bn_finalize<<<128, 256, 0, stream>>>(PS, gs0b, bs0b, SC0b, SH0b, 128, 1, 4 * 8192);

    out_bn_tr<<<dim3(8192 / 32, 128 / 32, 4), 256, 0, stream>>>(XS, OUT, SC0b, SH0b, 128, 8192);
}

// Round 4
// 241.029 us; speedup vs baseline: 5.0929x; 1.6391x over previous
//
#include <hip/hip_runtime.h>
#include <math.h>

#define BN_EPS 1e-5f

typedef float f32x4 __attribute__((ext_vector_type(4)));
typedef short s16x8 __attribute__((ext_vector_type(8)));
typedef short s16x4 __attribute__((ext_vector_type(4)));

__device__ __forceinline__ unsigned short f2bf(float f) {
    unsigned u = __builtin_bit_cast(unsigned, f);
    u = u + 0x7FFFu + ((u >> 16) & 1u);
    return (unsigned short)(u >> 16);
}
__device__ __forceinline__ float bf2f(unsigned short s) {
    unsigned u = ((unsigned)s) << 16;
    return __builtin_bit_cast(float, u);
}

__device__ __forceinline__ void gload16(const void* g, void* l) {
    __builtin_amdgcn_global_load_lds((const __attribute__((address_space(1))) unsigned int*)g,
                                     (__attribute__((address_space(3))) unsigned int*)l,
                                     16, 0, 0);
}

// ---------------- class-embedding MLP: 16 -> 64 (BN+GELU) -> 128 ----------------
__global__ __launch_bounds__(512) void cls_kernel(const int* __restrict__ lbl,
                                                  const float* __restrict__ Wc1,
                                                  const float* __restrict__ gc,
                                                  const float* __restrict__ bc,
                                                  const float* __restrict__ Wc2,
                                                  float* __restrict__ cls_vec) {
    __shared__ float h[4 * 64];
    __shared__ float act[4 * 64];
    int tid = threadIdx.x;
    if (tid < 256) {
        int b = tid >> 6, c = tid & 63;
        h[b * 64 + c] = Wc1[c * 16 + lbl[b]];
    }
    __syncthreads();
    if (tid < 64) {
        int c = tid;
        float m = 0.f;
        for (int b = 0; b < 4; b++) m += h[b * 64 + c];
        m *= 0.25f;
        float v = 0.f;
        for (int b = 0; b < 4; b++) { float d = h[b * 64 + c] - m; v += d * d; }
        v *= 0.25f;
        float sc = gc[c] * rsqrtf(v + BN_EPS);
        float sh = bc[c] - m * sc;
        for (int b = 0; b < 4; b++) {
            float x = h[b * 64 + c] * sc + sh;
            act[b * 64 + c] = 0.5f * x * (1.f + erff(x * 0.70710678118654752f));
        }
    }
    __syncthreads();
    int b = tid >> 7, o = tid & 127;
    float s = 0.f;
    for (int c = 0; c < 64; c++) s += Wc2[o * 64 + c] * act[b * 64 + c];
    cls_vec[b * 128 + o] = s;
}

// ---------------- transpose (B,C,N) fp32 -> (B,N,C) bf16, optional per-channel add ----------------
__global__ __launch_bounds__(256) void transpose_cp(const float* __restrict__ in,
                                                    unsigned short* __restrict__ out,
                                                    const float* __restrict__ addv,
                                                    int C, int N) {
    __shared__ float t[32][33];
    int b = blockIdx.z;
    int n0 = blockIdx.x * 32, c0 = blockIdx.y * 32;
    int i = threadIdx.x & 31, jj = threadIdx.x >> 5;
#pragma unroll
    for (int j = jj; j < 32; j += 8) {
        float v = in[((size_t)b * C + c0 + j) * N + n0 + i];
        if (addv) v += addv[b * C + c0 + j];
        t[j][i] = v;
    }
    __syncthreads();
    int j2 = threadIdx.x & 31, i2b = threadIdx.x >> 5;
#pragma unroll
    for (int i2 = i2b; i2 < 32; i2 += 8)
        out[((size_t)b * N + n0 + i2) * C + c0 + j2] = f2bf(t[j2][i2]);
}

// ---------------- 3-NN: 8 lanes per dense point, butterfly merge ----------------
#define KLESS(d, i, dd, ii) ((d) < (dd) || ((d) == (dd) && (i) < (ii)))
__global__ __launch_bounds__(256) void knn_kernel(const float* __restrict__ pd,
                                                  const float* __restrict__ ps,
                                                  int N1, int N2,
                                                  int* __restrict__ idx,
                                                  float* __restrict__ w) {
    __shared__ float sp[2048 * 3];
    int b = blockIdx.y;
    int tid = threadIdx.x;
    for (int t = tid; t < N2 * 3; t += 256) sp[t] = ps[(size_t)b * N2 * 3 + t];
    __syncthreads();
    int sub = tid & 7;
    int n = blockIdx.x * 32 + (tid >> 3);
    size_t pb = ((size_t)b * N1 + n) * 3;
    float px = pd[pb], py = pd[pb + 1], pz = pd[pb + 2];
    float d0 = 3.4e38f, d1 = 3.4e38f, d2 = 3.4e38f;
    int i0 = -1, i1 = -1, i2 = -1;
    for (int j = sub; j < N2; j += 8) {
        float dx = px - sp[j * 3], dy = py - sp[j * 3 + 1], dz = pz - sp[j * 3 + 2];
        float d = dx * dx + dy * dy + dz * dz;
        if (d < d2) {
            if (d < d0) { d2 = d1; i2 = i1; d1 = d0; i1 = i0; d0 = d; i0 = j; }
            else if (d < d1) { d2 = d1; i2 = i1; d1 = d; i1 = j; }
            else { d2 = d; i2 = j; }
        }
    }
#pragma unroll
    for (int m = 1; m < 8; m <<= 1) {
        float e0 = __shfl_xor(d0, m), e1 = __shfl_xor(d1, m), e2 = __shfl_xor(d2, m);
        int j0 = __shfl_xor(i0, m), j1 = __shfl_xor(i1, m), j2 = __shfl_xor(i2, m);
        if (KLESS(e0, j0, d2, i2)) {
            if (KLESS(e0, j0, d0, i0)) { d2 = d1; i2 = i1; d1 = d0; i1 = i0; d0 = e0; i0 = j0; }
            else if (KLESS(e0, j0, d1, i1)) { d2 = d1; i2 = i1; d1 = e0; i1 = j0; }
            else { d2 = e0; i2 = j0; }
        }
        if (KLESS(e1, j1, d2, i2)) {
            if (KLESS(e1, j1, d0, i0)) { d2 = d1; i2 = i1; d1 = d0; i1 = i0; d0 = e1; i0 = j1; }
            else if (KLESS(e1, j1, d1, i1)) { d2 = d1; i2 = i1; d1 = e1; i1 = j1; }
            else { d2 = e1; i2 = j1; }
        }
        if (KLESS(e2, j2, d2, i2)) {
            if (KLESS(e2, j2, d0, i0)) { d2 = d1; i2 = i1; d1 = d0; i1 = i0; d0 = e2; i0 = j2; }
            else if (KLESS(e2, j2, d1, i1)) { d2 = d1; i2 = i1; d1 = e2; i1 = j2; }
            else { d2 = e2; i2 = j2; }
        }
    }
    if (sub == 0) {
        float w0 = 1.f / (d0 + 1e-8f), w1 = 1.f / (d1 + 1e-8f), w2 = 1.f / (d2 + 1e-8f);
        float s = 1.f / (w0 + w1 + w2);
        size_t o = ((size_t)b * N1 + n) * 3;
        idx[o] = i0; idx[o + 1] = i1; idx[o + 2] = i2;
        w[o] = w0 * s; w[o + 1] = w1 * s; w[o + 2] = w2 * s;
    }
}

// ---------------- build x (point-major): XS[b][n][c] = skipT | interp(fsT) (raw) ----------------
__global__ __launch_bounds__(256) void build_x(const unsigned short* __restrict__ skipT,
                                               const unsigned short* __restrict__ fsT,
                                               const int* __restrict__ idx,
                                               const float* __restrict__ w,
                                               unsigned short* __restrict__ x,
                                               int Cskip, int Ctot, int Csp, int N1, int N2) {
    int cq = Ctot >> 2;
    size_t gid = (size_t)blockIdx.x * 256 + threadIdx.x;
    if (gid >= (size_t)4 * N1 * cq) return;
    int c = (int)(gid % cq) * 4;
    int n = (int)((gid / cq) % N1);
    int b = (int)(gid / ((size_t)cq * N1));
    s16x4 o;
    if (c < Cskip) {
        o = *(const s16x4*)(skipT + ((size_t)b * N1 + n) * Cskip + c);
    } else {
        int c2 = c - Cskip;
        size_t ob = ((size_t)b * N1 + n) * 3;
        int i0 = idx[ob], i1 = idx[ob + 1], i2 = idx[ob + 2];
        float w0 = w[ob], w1 = w[ob + 1], w2 = w[ob + 2];
        const unsigned short* f0 = fsT + ((size_t)b * N2 + i0) * Csp + c2;
        const unsigned short* f1 = fsT + ((size_t)b * N2 + i1) * Csp + c2;
        const unsigned short* f2 = fsT + ((size_t)b * N2 + i2) * Csp + c2;
        s16x4 v0 = *(const s16x4*)f0, v1 = *(const s16x4*)f1, v2 = *(const s16x4*)f2;
#pragma unroll
        for (int j = 0; j < 4; j++) {
            float v = w0 * bf2f((unsigned short)v0[j]) + w1 * bf2f((unsigned short)v1[j]) + w2 * bf2f((unsigned short)v2[j]);
            o[j] = (short)f2bf(v);
        }
    }
    *(s16x4*)(x + ((size_t)b * N1 + n) * Ctot + c) = o;
}

// ---------------- weight prep: fold per-k BN affine into weights; emit bf16 W + fp32 bias ----------------
__global__ __launch_bounds__(256) void wprep(const float* __restrict__ W,
                                             const float* __restrict__ sc,
                                             const float* __restrict__ sh,
                                             unsigned short* __restrict__ Wb,
                                             float* __restrict__ bias,
                                             int K, int kStart) {
    int m = blockIdx.x;
    int tid = threadIdx.x;
    float bsum = 0.f;
    for (int k = tid; k < K; k += 256) {
        float wv = W[(size_t)m * K + k];
        float o = wv;
        if (sc && k >= kStart) {
            o = wv * sc[k - kStart];
            bsum += wv * sh[k - kStart];
        }
        Wb[(size_t)m * K + k] = f2bf(o);
    }
    __shared__ float ls[256];
    ls[tid] = bsum;
    __syncthreads();
    for (int o = 128; o > 0; o >>= 1) {
        if (tid < o) ls[tid] += ls[tid + o];
        __syncthreads();
    }
    if (tid == 0) bias[m] = ls[0];
}

// ---------------- bf16 MFMA GEMM, 64x64 tile, 4 waves, dbuf + global_load_lds + counted vmcnt ----------
// OutT[n][m] = sum_k XT[n][k]*Wb[m][k] + bias[m]; batch folded into n (BN rows).
// Epilogue partial stats -> ps[(by*gridX+bx)*128 + ch*2 + {0,1}], ch = local channel 0..63.
__global__ __launch_bounds__(256) void gemm64(const unsigned short* __restrict__ XT,
                                              const unsigned short* __restrict__ Wb,
                                              const float* __restrict__ bias,
                                              unsigned short* __restrict__ OutT,
                                              float* __restrict__ ps,
                                              int BN, int K, int M) {
    __shared__ unsigned short As[2][64 * 32];
    __shared__ unsigned short Bs[2][64 * 32];
    __shared__ float sred[2][2][32][2];
    int tid = threadIdx.x;
    int lane = tid & 63, wid = tid >> 6;
    int wn = wid & 1, wm = wid >> 1;
    int bx = blockIdx.x, by = blockIdx.y;

    // staging: wave wid covers rows wid*16..wid*16+15; lane l -> row wid*16 + l/4, kcol (l&3)*8
    int srow = (wid << 4) + (lane >> 2);
    int skcol = (lane & 3) << 3;
    const unsigned short* gA = XT + (size_t)(bx * 64 + srow) * K + skcol;
    const unsigned short* gB = Wb + (size_t)(by * 64 + srow) * K + skcol;

    f32x4 acc[2][2];
#pragma unroll
    for (int i = 0; i < 2; i++)
#pragma unroll
        for (int j = 0; j < 2; j++) acc[i][j] = (f32x4)0.f;

    int nt = K >> 5;
    // prologue: stage buf0
    gload16(gA, &As[0][wid * 512]);
    gload16(gB, &Bs[0][wid * 512]);

    int r16 = lane & 15, q = lane >> 4;
    for (int t = 0; t < nt; t++) {
        int cur = t & 1;
        if (t + 1 < nt) {
            int k0 = (t + 1) << 5;
            gload16(gA + k0, &As[cur ^ 1][wid * 512]);
            gload16(gB + k0, &Bs[cur ^ 1][wid * 512]);
            asm volatile("s_waitcnt vmcnt(2)" ::: "memory");
        } else {
            asm volatile("s_waitcnt vmcnt(0)" ::: "memory");
        }
        __syncthreads();
        s16x8 afr[2], bfr[2];
        afr[0] = *(const s16x8*)&As[cur][(wn * 32 + r16) * 32 + q * 8];
        afr[1] = *(const s16x8*)&As[cur][(wn * 32 + 16 + r16) * 32 + q * 8];
        bfr[0] = *(const s16x8*)&Bs[cur][(wm * 32 + r16) * 32 + q * 8];
        bfr[1] = *(const s16x8*)&Bs[cur][(wm * 32 + 16 + r16) * 32 + q * 8];
        asm volatile("s_waitcnt lgkmcnt(0)" ::: "memory");
        __builtin_amdgcn_sched_barrier(0);
        __syncthreads();
#pragma unroll
        for (int i = 0; i < 2; i++)
#pragma unroll
            for (int j = 0; j < 2; j++)
                acc[i][j] = __builtin_amdgcn_mfma_f32_16x16x32_bf16(afr[i], bfr[j], acc[i][j], 0, 0, 0);
    }

    // epilogue: add bias, store bf16, partial stats
    int mc0 = by * 64 + wm * 32 + r16;
    float bv[2] = { bias[mc0], bias[mc0 + 16] };
    unsigned short* Ob = OutT + (size_t)(bx * 64) * M + by * 64;
    float s[2] = {0.f, 0.f}, qq[2] = {0.f, 0.f};
#pragma unroll
    for (int i = 0; i < 2; i++) {
#pragma unroll
        for (int j = 0; j < 2; j++) {
            int mcol = wm * 32 + j * 16 + r16;
#pragma unroll
            for (int r = 0; r < 4; r++) {
                float v = acc[i][j][r] + bv[j];
                s[j] += v; qq[j] += v * v;
                int n = wn * 32 + i * 16 + q * 4 + r;
                Ob[(size_t)n * M + mcol] = f2bf(v);
            }
        }
    }
#pragma unroll
    for (int j = 0; j < 2; j++) {
        s[j] += __shfl_xor(s[j], 16); s[j] += __shfl_xor(s[j], 32);
        qq[j] += __shfl_xor(qq[j], 16); qq[j] += __shfl_xor(qq[j], 32);
    }
    if (lane < 16) {
#pragma unroll
        for (int j = 0; j < 2; j++) {
            sred[wn][wm][j * 16 + lane][0] = s[j];
            sred[wn][wm][j * 16 + lane][1] = qq[j];
        }
    }
    __syncthreads();
    if (tid < 64) {
        int wmm = tid >> 5, c = tid & 31;
        float ssum = sred[0][wmm][c][0] + sred[1][wmm][c][0];
        float qsum = sred[0][wmm][c][1] + sred[1][wmm][c][1];
        size_t blin = (size_t)by * gridDim.x + bx;
        ps[blin * 128 + tid * 2] = ssum;
        ps[blin * 128 + tid * 2 + 1] = qsum;
    }
}

// ---------------- finalize BN: one block per channel ----------------
__global__ __launch_bounds__(256) void bn_finalize(const float* __restrict__ ps,
                                                   const float* __restrict__ g,
                                                   const float* __restrict__ bb,
                                                   float* __restrict__ sc,
                                                   float* __restrict__ sh,
                                                   int gx, int Npts) {
    int m = blockIdx.x;
    int by = m >> 6, ch = m & 63;
    float s = 0.f, q = 0.f;
    for (int bxi = threadIdx.x; bxi < gx; bxi += 256) {
        size_t blin = (size_t)by * gx + bxi;
        s += ps[blin * 128 + ch * 2];
        q += ps[blin * 128 + ch * 2 + 1];
    }
    __shared__ float ls[256], lq[256];
    ls[threadIdx.x] = s; lq[threadIdx.x] = q;
    __syncthreads();
    for (int o = 128; o > 0; o >>= 1) {
        if (threadIdx.x < o) { ls[threadIdx.x] += ls[threadIdx.x + o]; lq[threadIdx.x] += lq[threadIdx.x + o]; }
        __syncthreads();
    }
    if (threadIdx.x == 0) {
        float inv = 1.f / (float)Npts;
        float mean = ls[0] * inv;
        float var = fmaxf(lq[0] * inv - mean * mean, 0.f);
        float scale = g[m] * rsqrtf(var + BN_EPS);
        sc[m] = scale;
        sh[m] = bb[m] - mean * scale;
    }
}

// ---------------- final: (B,N,M) bf16 -> (B,M,N) fp32 with BN affine ----------------
__global__ __launch_bounds__(256) void out_bn_tr(const unsigned short* __restrict__ in,
                                                 float* __restrict__ out,
                                                 const float* __restrict__ sc,
                                                 const float* __restrict__ sh,
                                                 int M, int N) {
    __shared__ float t[32][33];
    int b = blockIdx.z;
    int n0 = blockIdx.x * 32, m0 = blockIdx.y * 32;
    int j = threadIdx.x & 31, ii = threadIdx.x >> 5;
#pragma unroll
    for (int i = ii; i < 32; i += 8)
        t[i][j] = bf2f(in[((size_t)b * N + n0 + i) * M + m0 + j]);
    __syncthreads();
    int i2 = threadIdx.x & 31, j2b = threadIdx.x >> 5;
#pragma unroll
    for (int j2 = j2b; j2 < 32; j2 += 8)
        out[((size_t)b * M + m0 + j2) * N + n0 + i2] = t[i2][j2] * sc[m0 + j2] + sh[m0 + j2];
}

extern "C" void kernel_launch(void* const* d_in, const int* in_sizes, int n_in,
                              void* d_out, int out_size, void* d_ws, size_t ws_size,
                              hipStream_t stream) {
    const float* p1 = (const float*)d_in[1];
    const float* p2 = (const float*)d_in[2];
    const float* p3 = (const float*)d_in[3];
    const float* p4 = (const float*)d_in[4];
    const float* f1 = (const float*)d_in[5];
    const float* f2 = (const float*)d_in[6];
    const float* f3 = (const float*)d_in[7];
    const float* f4 = (const float*)d_in[8];
    const int* cls = (const int*)d_in[9];
    const float* Wc1 = (const float*)d_in[10];
    const float* gc  = (const float*)d_in[11];
    const float* bc  = (const float*)d_in[12];
    const float* Wc2 = (const float*)d_in[13];
    const float* Ws2a = (const float*)d_in[14];
    const float* gs2a = (const float*)d_in[15];
    const float* bs2a = (const float*)d_in[16];
    const float* Ws2b = (const float*)d_in[17];
    const float* gs2b = (const float*)d_in[18];
    const float* bs2b = (const float*)d_in[19];
    const float* Ws1a = (const float*)d_in[20];
    const float* gs1a = (const float*)d_in[21];
    const float* bs1a = (const float*)d_in[22];
    const float* Ws1b = (const float*)d_in[23];
    const float* gs1b = (const float*)d_in[24];
    const float* bs1b = (const float*)d_in[25];
    const float* Ws0a = (const float*)d_in[26];
    const float* gs0a = (const float*)d_in[27];
    const float* bs0a = (const float*)d_in[28];
    const float* Ws0b = (const float*)d_in[29];
    const float* gs0b = (const float*)d_in[30];
    const float* bs0b = (const float*)d_in[31];

    char* ws = (char*)d_ws;
    size_t off = 0;
    auto alloc = [&](size_t bytes) { char* p = ws + off; off += (bytes + 255) & ~(size_t)255; return p; };
    unsigned short* F4T = (unsigned short*)alloc((size_t)4 * 128 * 1024 * 2);
    unsigned short* F3T = (unsigned short*)alloc((size_t)4 * 512 * 512 * 2);
    unsigned short* F2T = (unsigned short*)alloc((size_t)4 * 2048 * 256 * 2);
    unsigned short* F1T = (unsigned short*)alloc((size_t)4 * 8192 * 128 * 2);
    unsigned short* XS  = (unsigned short*)alloc((size_t)4 * 8192 * 384 * 2);
    unsigned short* YA  = (unsigned short*)alloc((size_t)4 * 8192 * 128 * 2);
    unsigned short* FN2 = (unsigned short*)alloc((size_t)4 * 512 * 512 * 2);
    unsigned short* FN1 = (unsigned short*)alloc((size_t)4 * 2048 * 256 * 2);
    unsigned short* XO  = (unsigned short*)alloc((size_t)4 * 8192 * 128 * 2);
    unsigned short* WB2a = (unsigned short*)alloc((size_t)512 * 1536 * 2);
    unsigned short* WB2b = (unsigned short*)alloc((size_t)512 * 512 * 2);
    unsigned short* WB1a = (unsigned short*)alloc((size_t)256 * 768 * 2);
    unsigned short* WB1b = (unsigned short*)alloc((size_t)256 * 256 * 2);
    unsigned short* WB0a = (unsigned short*)alloc((size_t)128 * 384 * 2);
    unsigned short* WB0b = (unsigned short*)alloc((size_t)128 * 128 * 2);
    float* BI2a = (float*)alloc(512 * 4); float* BI2b = (float*)alloc(512 * 4);
    float* BI1a = (float*)alloc(256 * 4); float* BI1b = (float*)alloc(256 * 4);
    float* BI0a = (float*)alloc(128 * 4); float* BI0b = (float*)alloc(128 * 4);
    int*   IDX = (int*)alloc((size_t)4 * 8192 * 3 * 4);
    float* WGT = (float*)alloc((size_t)4 * 8192 * 3 * 4);
    float* CLSV = (float*)alloc(4 * 128 * 4);
    float* PS = (float*)alloc((size_t)1024 * 128 * 4);
    float* SC2a = (float*)alloc(512 * 4); float* SH2a = (float*)alloc(512 * 4);
    float* SC2b = (float*)alloc(512 * 4); float* SH2b = (float*)alloc(512 * 4);
    float* SC1a = (float*)alloc(512 * 4); float* SH1a = (float*)alloc(512 * 4);
    float* SC1b = (float*)alloc(512 * 4); float* SH1b = (float*)alloc(512 * 4);
    float* SC0a = (float*)alloc(512 * 4); float* SH0a = (float*)alloc(512 * 4);
    float* SC0b = (float*)alloc(512 * 4); float* SH0b = (float*)alloc(512 * 4);
    float* OUT = (float*)d_out;

    cls_kernel<<<1, 512, 0, stream>>>(cls, Wc1, gc, bc, Wc2, CLSV);
    transpose_cp<<<dim3(128 / 32, 1024 / 32, 4), 256, 0, stream>>>(f4, F4T, nullptr, 1024, 128);
    transpose_cp<<<dim3(512 / 32, 512 / 32, 4), 256, 0, stream>>>(f3, F3T, nullptr, 512, 512);
    transpose_cp<<<dim3(2048 / 32, 256 / 32, 4), 256, 0, stream>>>(f2, F2T, nullptr, 256, 2048);
    transpose_cp<<<dim3(8192 / 32, 128 / 32, 4), 256, 0, stream>>>(f1, F1T, CLSV, 128, 8192);

    // ---- stage s2: BN=2048 rows, K=1536 -> M=512, then K=512 -> 512
    wprep<<<512, 256, 0, stream>>>(Ws2a, nullptr, nullptr, WB2a, BI2a, 1536, 0);
    knn_kernel<<<dim3(512 / 32, 4), 256, 0, stream>>>(p3, p4, 512, 128, IDX, WGT);
    build_x<<<(int)(((size_t)4 * 512 * (1536 / 4) + 255) / 256), 256, 0, stream>>>(
        F3T, F4T, IDX, WGT, XS, 512, 1536, 1024, 512, 128);
    gemm64<<<dim3(32, 8), 256, 0, stream>>>(XS, WB2a, BI2a, YA, PS, 2048, 1536, 512);
    bn_finalize<<<512, 256, 0, stream>>>(PS, gs2a, bs2a, SC2a, SH2a, 32, 2048);
    wprep<<<512, 256, 0, stream>>>(Ws2b, SC2a, SH2a, WB2b, BI2b, 512, 0);
    gemm64<<<dim3(32, 8), 256, 0, stream>>>(YA, WB2b, BI2b, FN2, PS, 2048, 512, 512);
    bn_finalize<<<512, 256, 0, stream>>>(PS, gs2b, bs2b, SC2b, SH2b, 32, 2048);

    // ---- stage s1: BN=8192 rows, K=768 -> 256, K=256 -> 256
    wprep<<<256, 256, 0, stream>>>(Ws1a, SC2b, SH2b, WB1a, BI1a, 768, 256);
    knn_kernel<<<dim3(2048 / 32, 4), 256, 0, stream>>>(p2, p3, 2048, 512, IDX, WGT);
    build_x<<<(int)(((size_t)4 * 2048 * (768 / 4) + 255) / 256), 256, 0, stream>>>(
        F2T, FN2, IDX, WGT, XS, 256, 768, 512, 2048, 512);
    gemm64<<<dim3(128, 4), 256, 0, stream>>>(XS, WB1a, BI1a, YA, PS, 8192, 768, 256);
    bn_finalize<<<256, 256, 0, stream>>>(PS, gs1a, bs1a, SC1a, SH1a, 128, 8192);
    wprep<<<256, 256, 0, stream>>>(Ws1b, SC1a, SH1a, WB1b, BI1b, 256, 0);
    gemm64<<<dim3(128, 4), 256, 0, stream>>>(YA, WB1b, BI1b, FN1, PS, 8192, 256, 256);
    bn_finalize<<<256, 256, 0, stream>>>(PS, gs1b, bs1b, SC1b, SH1b, 128, 8192);

    // ---- stage s0: BN=32768 rows, K=384 -> 128, K=128 -> 128
    wprep<<<128, 256, 0, stream>>>(Ws0a, SC1b, SH1b, WB0a, BI0a, 384, 128);
    knn_kernel<<<dim3(8192 / 32, 4), 256, 0, stream>>>(p1, p2, 8192, 2048, IDX, WGT);
    build_x<<<(int)(((size_t)4 * 8192 * (384 / 4) + 255) / 256), 256, 0, stream>>>(
        F1T, FN1, IDX, WGT, XS, 128, 384, 256, 8192, 2048);
    gemm64<<<dim3(512, 2), 256, 0, stream>>>(XS, WB0a, BI0a, YA, PS, 32768, 384, 128);
    bn_finalize<<<128, 256, 0, stream>>>(PS, gs0a, bs0a, SC0a, SH0a, 512, 32768);
    wprep<<<128, 256, 0, stream>>>(Ws0b, SC0a, SH0a, WB0b, BI0b, 128, 0);
    gemm64<<<dim3(512, 2), 256, 0, stream>>>(YA, WB0b, BI0b, XO, PS, 32768, 128, 128);
    bn_finalize<<<128, 256, 0, stream>>>(PS, gs0b, bs0b, SC0b, SH0b, 512, 32768);

    out_bn_tr<<<dim3(8192 / 32, 128 / 32, 4), 256, 0, stream>>>(XO, OUT, SC0b, SH0b, 128, 8192);
}

// Round 6
// 220.191 us; speedup vs baseline: 5.5749x; 1.0946x over previous
//
#include <hip/hip_runtime.h>
#include <math.h>

#define BN_EPS 1e-5f

typedef float f32x4 __attribute__((ext_vector_type(4)));
typedef short s16x8 __attribute__((ext_vector_type(8)));
typedef short s16x4 __attribute__((ext_vector_type(4)));

__device__ __forceinline__ unsigned short f2bf(float f) {
    unsigned u = __builtin_bit_cast(unsigned, f);
    u = u + 0x7FFFu + ((u >> 16) & 1u);
    return (unsigned short)(u >> 16);
}
__device__ __forceinline__ float bf2f(unsigned short s) {
    unsigned u = ((unsigned)s) << 16;
    return __builtin_bit_cast(float, u);
}

__device__ __forceinline__ void gload16(const void* g, void* l) {
    __builtin_amdgcn_global_load_lds((const __attribute__((address_space(1))) unsigned int*)g,
                                     (__attribute__((address_space(3))) unsigned int*)l,
                                     16, 0, 0);
}

// ---------------- class-embedding MLP: 16 -> 64 (BN+GELU) -> 128 ----------------
__global__ __launch_bounds__(512) void cls_kernel(const int* __restrict__ lbl,
                                                  const float* __restrict__ Wc1,
                                                  const float* __restrict__ gc,
                                                  const float* __restrict__ bc,
                                                  const float* __restrict__ Wc2,
                                                  float* __restrict__ cls_vec) {
    __shared__ float h[4 * 64];
    __shared__ float act[4 * 64];
    int tid = threadIdx.x;
    if (tid < 256) {
        int b = tid >> 6, c = tid & 63;
        h[b * 64 + c] = Wc1[c * 16 + lbl[b]];
    }
    __syncthreads();
    if (tid < 64) {
        int c = tid;
        float m = 0.f;
        for (int b = 0; b < 4; b++) m += h[b * 64 + c];
        m *= 0.25f;
        float v = 0.f;
        for (int b = 0; b < 4; b++) { float d = h[b * 64 + c] - m; v += d * d; }
        v *= 0.25f;
        float sc = gc[c] * rsqrtf(v + BN_EPS);
        float sh = bc[c] - m * sc;
        for (int b = 0; b < 4; b++) {
            float x = h[b * 64 + c] * sc + sh;
            act[b * 64 + c] = 0.5f * x * (1.f + erff(x * 0.70710678118654752f));
        }
    }
    __syncthreads();
    int b = tid >> 7, o = tid & 127;
    float s = 0.f;
    for (int c = 0; c < 64; c++) s += Wc2[o * 64 + c] * act[b * 64 + c];
    cls_vec[b * 128 + o] = s;
}

// ---------------- transpose (B,C,N) fp32 -> (B,N,C) bf16, optional per-channel add ----------------
__global__ __launch_bounds__(256) void transpose_cp(const float* __restrict__ in,
                                                    unsigned short* __restrict__ out,
                                                    const float* __restrict__ addv,
                                                    int C, int N) {
    __shared__ float t[32][33];
    int b = blockIdx.z;
    int n0 = blockIdx.x * 32, c0 = blockIdx.y * 32;
    int i = threadIdx.x & 31, jj = threadIdx.x >> 5;
#pragma unroll
    for (int j = jj; j < 32; j += 8) {
        float v = in[((size_t)b * C + c0 + j) * N + n0 + i];
        if (addv) v += addv[b * C + c0 + j];
        t[j][i] = v;
    }
    __syncthreads();
    int j2 = threadIdx.x & 31, i2b = threadIdx.x >> 5;
#pragma unroll
    for (int i2 = i2b; i2 < 32; i2 += 8)
        out[((size_t)b * N + n0 + i2) * C + c0 + j2] = f2bf(t[j2][i2]);
}

// ---------------- 3-NN: branchless exact-precision top-3, 8 lanes/point ----------------
// Scan: compare-exchange on (float d, int j), strict < (incumbent smaller-j wins ties).
// Merge: exact u64 keys (bits(d)<<32 | j) -> exact distance order + smaller-index tie-break.
__global__ __launch_bounds__(256) void knn_kernel(const float* __restrict__ pd,
                                                  const float* __restrict__ ps,
                                                  int N1, int N2,
                                                  int* __restrict__ idx,
                                                  float* __restrict__ w) {
    __shared__ float spx[2048], spy[2048], spz[2048];
    int b = blockIdx.y;
    int tid = threadIdx.x;
    for (int t = tid; t < N2; t += 256) {
        size_t base = ((size_t)b * N2 + t) * 3;
        spx[t] = ps[base];
        spy[t] = ps[base + 1];
        spz[t] = ps[base + 2];
    }
    __syncthreads();
    int sub = tid & 7;
    int n = blockIdx.x * 32 + (tid >> 3);
    size_t pb = ((size_t)b * N1 + n) * 3;
    float px = pd[pb], py = pd[pb + 1], pz = pd[pb + 2];
    float d0 = 3.4e38f, d1 = 3.4e38f, d2 = 3.4e38f;
    int i0 = 0, i1 = 0, i2 = 0;
#pragma unroll 4
    for (int j = sub; j < N2; j += 8) {
        float dx = px - spx[j], dy = py - spy[j], dz = pz - spz[j];
        float d = dx * dx + dy * dy + dz * dz;
        // branchless sorted insert (strict <, candidate has largest j so ties keep incumbent)
        bool c2 = d < d2;
        float nd = c2 ? d : d2;  int ni = c2 ? j : i2;
        bool c1 = nd < d1;
        float t1 = c1 ? nd : d1; int ti1 = c1 ? ni : i1;
        float t2 = c1 ? d1 : nd; int ti2 = c1 ? i1 : ni;
        bool c0 = t1 < d0;
        d2 = t2; i2 = ti2;
        d1 = c0 ? d0 : t1; i1 = c0 ? i0 : ti1;
        d0 = c0 ? t1 : d0; i0 = c0 ? ti1 : i0;
    }
    // pack exact keys for merge
    unsigned long long k0 = ((unsigned long long)__builtin_bit_cast(unsigned, d0) << 32) | (unsigned)i0;
    unsigned long long k1 = ((unsigned long long)__builtin_bit_cast(unsigned, d1) << 32) | (unsigned)i1;
    unsigned long long k2 = ((unsigned long long)__builtin_bit_cast(unsigned, d2) << 32) | (unsigned)i2;
#pragma unroll
    for (int m = 1; m < 8; m <<= 1) {
        unsigned long long e0, e1, e2;
        { int lo = __shfl_xor((int)(unsigned)(k0 & 0xFFFFFFFFull), m), hi = __shfl_xor((int)(unsigned)(k0 >> 32), m);
          e0 = ((unsigned long long)(unsigned)hi << 32) | (unsigned)lo; }
        { int lo = __shfl_xor((int)(unsigned)(k1 & 0xFFFFFFFFull), m), hi = __shfl_xor((int)(unsigned)(k1 >> 32), m);
          e1 = ((unsigned long long)(unsigned)hi << 32) | (unsigned)lo; }
        { int lo = __shfl_xor((int)(unsigned)(k2 & 0xFFFFFFFFull), m), hi = __shfl_xor((int)(unsigned)(k2 >> 32), m);
          e2 = ((unsigned long long)(unsigned)hi << 32) | (unsigned)lo; }
        unsigned long long t0, t1;
        t0 = k0 > e0 ? k0 : e0; k0 = k0 < e0 ? k0 : e0; t1 = k1 > t0 ? k1 : t0; k1 = k1 < t0 ? k1 : t0; k2 = k2 < t1 ? k2 : t1;
        t0 = k0 > e1 ? k0 : e1; k0 = k0 < e1 ? k0 : e1; t1 = k1 > t0 ? k1 : t0; k1 = k1 < t0 ? k1 : t0; k2 = k2 < t1 ? k2 : t1;
        t0 = k0 > e2 ? k0 : e2; k0 = k0 < e2 ? k0 : e2; t1 = k1 > t0 ? k1 : t0; k1 = k1 < t0 ? k1 : t0; k2 = k2 < t1 ? k2 : t1;
    }
    if (sub == 0) {
        float f0 = __builtin_bit_cast(float, (unsigned)(k0 >> 32));
        float f1 = __builtin_bit_cast(float, (unsigned)(k1 >> 32));
        float f2 = __builtin_bit_cast(float, (unsigned)(k2 >> 32));
        float w0 = 1.f / (f0 + 1e-8f), w1 = 1.f / (f1 + 1e-8f), w2 = 1.f / (f2 + 1e-8f);
        float s = 1.f / (w0 + w1 + w2);
        size_t o = ((size_t)b * N1 + n) * 3;
        idx[o] = (int)(unsigned)(k0 & 0xFFFFFFFFull);
        idx[o + 1] = (int)(unsigned)(k1 & 0xFFFFFFFFull);
        idx[o + 2] = (int)(unsigned)(k2 & 0xFFFFFFFFull);
        w[o] = w0 * s; w[o + 1] = w1 * s; w[o + 2] = w2 * s;
    }
}

// ---------------- build x (point-major): XS[b][n][c] = skipT | interp(fsT) (raw) ----------------
__global__ __launch_bounds__(256) void build_x(const unsigned short* __restrict__ skipT,
                                               const unsigned short* __restrict__ fsT,
                                               const int* __restrict__ idx,
                                               const float* __restrict__ w,
                                               unsigned short* __restrict__ x,
                                               int Cskip, int Ctot, int Csp, int N1, int N2) {
    int cq = Ctot >> 2;
    size_t gid = (size_t)blockIdx.x * 256 + threadIdx.x;
    if (gid >= (size_t)4 * N1 * cq) return;
    int c = (int)(gid % cq) * 4;
    int n = (int)((gid / cq) % N1);
    int b = (int)(gid / ((size_t)cq * N1));
    s16x4 o;
    if (c < Cskip) {
        o = *(const s16x4*)(skipT + ((size_t)b * N1 + n) * Cskip + c);
    } else {
        int c2 = c - Cskip;
        size_t ob = ((size_t)b * N1 + n) * 3;
        int i0 = idx[ob], i1 = idx[ob + 1], i2 = idx[ob + 2];
        float w0 = w[ob], w1 = w[ob + 1], w2 = w[ob + 2];
        const unsigned short* f0 = fsT + ((size_t)b * N2 + i0) * Csp + c2;
        const unsigned short* f1 = fsT + ((size_t)b * N2 + i1) * Csp + c2;
        const unsigned short* f2 = fsT + ((size_t)b * N2 + i2) * Csp + c2;
        s16x4 v0 = *(const s16x4*)f0, v1 = *(const s16x4*)f1, v2 = *(const s16x4*)f2;
#pragma unroll
        for (int j = 0; j < 4; j++) {
            float v = w0 * bf2f((unsigned short)v0[j]) + w1 * bf2f((unsigned short)v1[j]) + w2 * bf2f((unsigned short)v2[j]);
            o[j] = (short)f2bf(v);
        }
    }
    *(s16x4*)(x + ((size_t)b * N1 + n) * Ctot + c) = o;
}

// ---------------- weight prep: fold per-k BN affine into weights; emit bf16 W + fp32 bias ----------------
__global__ __launch_bounds__(256) void wprep(const float* __restrict__ W,
                                             const float* __restrict__ sc,
                                             const float* __restrict__ sh,
                                             unsigned short* __restrict__ Wb,
                                             float* __restrict__ bias,
                                             int K, int kStart) {
    int m = blockIdx.x;
    int tid = threadIdx.x;
    float bsum = 0.f;
    for (int k = tid; k < K; k += 256) {
        float wv = W[(size_t)m * K + k];
        float o = wv;
        if (sc && k >= kStart) {
            o = wv * sc[k - kStart];
            bsum += wv * sh[k - kStart];
        }
        Wb[(size_t)m * K + k] = f2bf(o);
    }
    __shared__ float ls[256];
    ls[tid] = bsum;
    __syncthreads();
    for (int o = 128; o > 0; o >>= 1) {
        if (tid < o) ls[tid] += ls[tid + o];
        __syncthreads();
    }
    if (tid == 0) bias[m] = ls[0];
}

// ---------------- bf16 MFMA GEMM, 64x64 tile, 4 waves, dbuf + global_load_lds + counted vmcnt ----------
__global__ __launch_bounds__(256) void gemm64(const unsigned short* __restrict__ XT,
                                              const unsigned short* __restrict__ Wb,
                                              const float* __restrict__ bias,
                                              unsigned short* __restrict__ OutT,
                                              float* __restrict__ ps,
                                              int BN, int K, int M) {
    __shared__ unsigned short As[2][64 * 32];
    __shared__ unsigned short Bs[2][64 * 32];
    __shared__ float sred[2][2][32][2];
    int tid = threadIdx.x;
    int lane = tid & 63, wid = tid >> 6;
    int wn = wid & 1, wm = wid >> 1;
    int bx = blockIdx.x, by = blockIdx.y;

    int srow = (wid << 4) + (lane >> 2);
    int skcol = (lane & 3) << 3;
    const unsigned short* gA = XT + (size_t)(bx * 64 + srow) * K + skcol;
    const unsigned short* gB = Wb + (size_t)(by * 64 + srow) * K + skcol;

    f32x4 acc[2][2];
#pragma unroll
    for (int i = 0; i < 2; i++)
#pragma unroll
        for (int j = 0; j < 2; j++) acc[i][j] = (f32x4)0.f;

    int nt = K >> 5;
    gload16(gA, &As[0][wid * 512]);
    gload16(gB, &Bs[0][wid * 512]);

    int r16 = lane & 15, q = lane >> 4;
    for (int t = 0; t < nt; t++) {
        int cur = t & 1;
        if (t + 1 < nt) {
            int k0 = (t + 1) << 5;
            gload16(gA + k0, &As[cur ^ 1][wid * 512]);
            gload16(gB + k0, &Bs[cur ^ 1][wid * 512]);
            asm volatile("s_waitcnt vmcnt(2)" ::: "memory");
        } else {
            asm volatile("s_waitcnt vmcnt(0)" ::: "memory");
        }
        __syncthreads();
        s16x8 afr[2], bfr[2];
        afr[0] = *(const s16x8*)&As[cur][(wn * 32 + r16) * 32 + q * 8];
        afr[1] = *(const s16x8*)&As[cur][(wn * 32 + 16 + r16) * 32 + q * 8];
        bfr[0] = *(const s16x8*)&Bs[cur][(wm * 32 + r16) * 32 + q * 8];
        bfr[1] = *(const s16x8*)&Bs[cur][(wm * 32 + 16 + r16) * 32 + q * 8];
        asm volatile("s_waitcnt lgkmcnt(0)" ::: "memory");
        __builtin_amdgcn_sched_barrier(0);
        __syncthreads();
#pragma unroll
        for (int i = 0; i < 2; i++)
#pragma unroll
            for (int j = 0; j < 2; j++)
                acc[i][j] = __builtin_amdgcn_mfma_f32_16x16x32_bf16(afr[i], bfr[j], acc[i][j], 0, 0, 0);
    }

    int mc0 = by * 64 + wm * 32 + r16;
    float bv[2] = { bias[mc0], bias[mc0 + 16] };
    unsigned short* Ob = OutT + (size_t)(bx * 64) * M + by * 64;
    float s[2] = {0.f, 0.f}, qq[2] = {0.f, 0.f};
#pragma unroll
    for (int i = 0; i < 2; i++) {
#pragma unroll
        for (int j = 0; j < 2; j++) {
            int mcol = wm * 32 + j * 16 + r16;
#pragma unroll
            for (int r = 0; r < 4; r++) {
                float v = acc[i][j][r] + bv[j];
                s[j] += v; qq[j] += v * v;
                int n = wn * 32 + i * 16 + q * 4 + r;
                Ob[(size_t)n * M + mcol] = f2bf(v);
            }
        }
    }
#pragma unroll
    for (int j = 0; j < 2; j++) {
        s[j] += __shfl_xor(s[j], 16); s[j] += __shfl_xor(s[j], 32);
        qq[j] += __shfl_xor(qq[j], 16); qq[j] += __shfl_xor(qq[j], 32);
    }
    if (lane < 16) {
#pragma unroll
        for (int j = 0; j < 2; j++) {
            sred[wn][wm][j * 16 + lane][0] = s[j];
            sred[wn][wm][j * 16 + lane][1] = qq[j];
        }
    }
    __syncthreads();
    if (tid < 64) {
        int wmm = tid >> 5, c = tid & 31;
        float ssum = sred[0][wmm][c][0] + sred[1][wmm][c][0];
        float qsum = sred[0][wmm][c][1] + sred[1][wmm][c][1];
        size_t blin = (size_t)by * gridDim.x + bx;
        ps[blin * 128 + tid * 2] = ssum;
        ps[blin * 128 + tid * 2 + 1] = qsum;
    }
}

// ---------------- finalize BN: one block per channel ----------------
__global__ __launch_bounds__(256) void bn_finalize(const float* __restrict__ ps,
                                                   const float* __restrict__ g,
                                                   const float* __restrict__ bb,
                                                   float* __restrict__ sc,
                                                   float* __restrict__ sh,
                                                   int gx, int Npts) {
    int m = blockIdx.x;
    int by = m >> 6, ch = m & 63;
    float s = 0.f, q = 0.f;
    for (int bxi = threadIdx.x; bxi < gx; bxi += 256) {
        size_t blin = (size_t)by * gx + bxi;
        s += ps[blin * 128 + ch * 2];
        q += ps[blin * 128 + ch * 2 + 1];
    }
    __shared__ float ls[256], lq[256];
    ls[threadIdx.x] = s; lq[threadIdx.x] = q;
    __syncthreads();
    for (int o = 128; o > 0; o >>= 1) {
        if (threadIdx.x < o) { ls[threadIdx.x] += ls[threadIdx.x + o]; lq[threadIdx.x] += lq[threadIdx.x + o]; }
        __syncthreads();
    }
    if (threadIdx.x == 0) {
        float inv = 1.f / (float)Npts;
        float mean = ls[0] * inv;
        float var = fmaxf(lq[0] * inv - mean * mean, 0.f);
        float scale = g[m] * rsqrtf(var + BN_EPS);
        sc[m] = scale;
        sh[m] = bb[m] - mean * scale;
    }
}

// ---------------- final: (B,N,M) bf16 -> (B,M,N) fp32 with BN affine ----------------
__global__ __launch_bounds__(256) void out_bn_tr(const unsigned short* __restrict__ in,
                                                 float* __restrict__ out,
                                                 const float* __restrict__ sc,
                                                 const float* __restrict__ sh,
                                                 int M, int N) {
    __shared__ float t[32][33];
    int b = blockIdx.z;
    int n0 = blockIdx.x * 32, m0 = blockIdx.y * 32;
    int j = threadIdx.x & 31, ii = threadIdx.x >> 5;
#pragma unroll
    for (int i = ii; i < 32; i += 8)
        t[i][j] = bf2f(in[((size_t)b * N + n0 + i) * M + m0 + j]);
    __syncthreads();
    int i2 = threadIdx.x & 31, j2b = threadIdx.x >> 5;
#pragma unroll
    for (int j2 = j2b; j2 < 32; j2 += 8)
        out[((size_t)b * M + m0 + j2) * N + n0 + i2] = t[i2][j2] * sc[m0 + j2] + sh[m0 + j2];
}

extern "C" void kernel_launch(void* const* d_in, const int* in_sizes, int n_in,
                              void* d_out, int out_size, void* d_ws, size_t ws_size,
                              hipStream_t stream) {
    const float* p1 = (const float*)d_in[1];
    const float* p2 = (const float*)d_in[2];
    const float* p3 = (const float*)d_in[3];
    const float* p4 = (const float*)d_in[4];
    const float* f1 = (const float*)d_in[5];
    const float* f2 = (const float*)d_in[6];
    const float* f3 = (const float*)d_in[7];
    const float* f4 = (const float*)d_in[8];
    const int* cls = (const int*)d_in[9];
    const float* Wc1 = (const float*)d_in[10];
    const float* gc  = (const float*)d_in[11];
    const float* bc  = (const float*)d_in[12];
    const float* Wc2 = (const float*)d_in[13];
    const float* Ws2a = (const float*)d_in[14];
    const float* gs2a = (const float*)d_in[15];
    const float* bs2a = (const float*)d_in[16];
    const float* Ws2b = (const float*)d_in[17];
    const float* gs2b = (const float*)d_in[18];
    const float* bs2b = (const float*)d_in[19];
    const float* Ws1a = (const float*)d_in[20];
    const float* gs1a = (const float*)d_in[21];
    const float* bs1a = (const float*)d_in[22];
    const float* Ws1b = (const float*)d_in[23];
    const float* gs1b = (const float*)d_in[24];
    const float* bs1b = (const float*)d_in[25];
    const float* Ws0a = (const float*)d_in[26];
    const float* gs0a = (const float*)d_in[27];
    const float* bs0a = (const float*)d_in[28];
    const float* Ws0b = (const float*)d_in[29];
    const float* gs0b = (const float*)d_in[30];
    const float* bs0b = (const float*)d_in[31];

    char* ws = (char*)d_ws;
    size_t off = 0;
    auto alloc = [&](size_t bytes) { char* p = ws + off; off += (bytes + 255) & ~(size_t)255; return p; };
    unsigned short* F4T = (unsigned short*)alloc((size_t)4 * 128 * 1024 * 2);
    unsigned short* F3T = (unsigned short*)alloc((size_t)4 * 512 * 512 * 2);
    unsigned short* F2T = (unsigned short*)alloc((size_t)4 * 2048 * 256 * 2);
    unsigned short* F1T = (unsigned short*)alloc((size_t)4 * 8192 * 128 * 2);
    unsigned short* XS  = (unsigned short*)alloc((size_t)4 * 8192 * 384 * 2);
    unsigned short* YA  = (unsigned short*)alloc((size_t)4 * 8192 * 128 * 2);
    unsigned short* FN2 = (unsigned short*)alloc((size_t)4 * 512 * 512 * 2);
    unsigned short* FN1 = (unsigned short*)alloc((size_t)4 * 2048 * 256 * 2);
    unsigned short* XO  = (unsigned short*)alloc((size_t)4 * 8192 * 128 * 2);
    unsigned short* WB2a = (unsigned short*)alloc((size_t)512 * 1536 * 2);
    unsigned short* WB2b = (unsigned short*)alloc((size_t)512 * 512 * 2);
    unsigned short* WB1a = (unsigned short*)alloc((size_t)256 * 768 * 2);
    unsigned short* WB1b = (unsigned short*)alloc((size_t)256 * 256 * 2);
    unsigned short* WB0a = (unsigned short*)alloc((size_t)128 * 384 * 2);
    unsigned short* WB0b = (unsigned short*)alloc((size_t)128 * 128 * 2);
    float* BI2a = (float*)alloc(512 * 4); float* BI2b = (float*)alloc(512 * 4);
    float* BI1a = (float*)alloc(256 * 4); float* BI1b = (float*)alloc(256 * 4);
    float* BI0a = (float*)alloc(128 * 4); float* BI0b = (float*)alloc(128 * 4);
    int*   IDX = (int*)alloc((size_t)4 * 8192 * 3 * 4);
    float* WGT = (float*)alloc((size_t)4 * 8192 * 3 * 4);
    float* CLSV = (float*)alloc(4 * 128 * 4);
    float* PS = (float*)alloc((size_t)1024 * 128 * 4);
    float* SC2a = (float*)alloc(512 * 4); float* SH2a = (float*)alloc(512 * 4);
    float* SC2b = (float*)alloc(512 * 4); float* SH2b = (float*)alloc(512 * 4);
    float* SC1a = (float*)alloc(512 * 4); float* SH1a = (float*)alloc(512 * 4);
    float* SC1b = (float*)alloc(512 * 4); float* SH1b = (float*)alloc(512 * 4);
    float* SC0a = (float*)alloc(512 * 4); float* SH0a = (float*)alloc(512 * 4);
    float* SC0b = (float*)alloc(512 * 4); float* SH0b = (float*)alloc(512 * 4);
    float* OUT = (float*)d_out;

    cls_kernel<<<1, 512, 0, stream>>>(cls, Wc1, gc, bc, Wc2, CLSV);
    transpose_cp<<<dim3(128 / 32, 1024 / 32, 4), 256, 0, stream>>>(f4, F4T, nullptr, 1024, 128);
    transpose_cp<<<dim3(512 / 32, 512 / 32, 4), 256, 0, stream>>>(f3, F3T, nullptr, 512, 512);
    transpose_cp<<<dim3(2048 / 32, 256 / 32, 4), 256, 0, stream>>>(f2, F2T, nullptr, 256, 2048);
    transpose_cp<<<dim3(8192 / 32, 128 / 32, 4), 256, 0, stream>>>(f1, F1T, CLSV, 128, 8192);

    // ---- stage s2: BN=2048 rows, K=1536 -> M=512, then K=512 -> 512
    wprep<<<512, 256, 0, stream>>>(Ws2a, nullptr, nullptr, WB2a, BI2a, 1536, 0);
    knn_kernel<<<dim3(512 / 32, 4), 256, 0, stream>>>(p3, p4, 512, 128, IDX, WGT);
    build_x<<<(int)(((size_t)4 * 512 * (1536 / 4) + 255) / 256), 256, 0, stream>>>(
        F3T, F4T, IDX, WGT, XS, 512, 1536, 1024, 512, 128);
    gemm64<<<dim3(32, 8), 256, 0, stream>>>(XS, WB2a, BI2a, YA, PS, 2048, 1536, 512);
    bn_finalize<<<512, 256, 0, stream>>>(PS, gs2a, bs2a, SC2a, SH2a, 32, 2048);
    wprep<<<512, 256, 0, stream>>>(Ws2b, SC2a, SH2a, WB2b, BI2b, 512, 0);
    gemm64<<<dim3(32, 8), 256, 0, stream>>>(YA, WB2b, BI2b, FN2, PS, 2048, 512, 512);
    bn_finalize<<<512, 256, 0, stream>>>(PS, gs2b, bs2b, SC2b, SH2b, 32, 2048);

    // ---- stage s1: BN=8192 rows, K=768 -> 256, K=256 -> 256
    wprep<<<256, 256, 0, stream>>>(Ws1a, SC2b, SH2b, WB1a, BI1a, 768, 256);
    knn_kernel<<<dim3(2048 / 32, 4), 256, 0, stream>>>(p2, p3, 2048, 512, IDX, WGT);
    build_x<<<(int)(((size_t)4 * 2048 * (768 / 4) + 255) / 256), 256, 0, stream>>>(
        F2T, FN2, IDX, WGT, XS, 256, 768, 512, 2048, 512);
    gemm64<<<dim3(128, 4), 256, 0, stream>>>(XS, WB1a, BI1a, YA, PS, 8192, 768, 256);
    bn_finalize<<<256, 256, 0, stream>>>(PS, gs1a, bs1a, SC1a, SH1a, 128, 8192);
    wprep<<<256, 256, 0, stream>>>(Ws1b, SC1a, SH1a, WB1b, BI1b, 256, 0);
    gemm64<<<dim3(128, 4), 256, 0, stream>>>(YA, WB1b, BI1b, FN1, PS, 8192, 256, 256);
    bn_finalize<<<256, 256, 0, stream>>>(PS, gs1b, bs1b, SC1b, SH1b, 128, 8192);

    // ---- stage s0: BN=32768 rows, K=384 -> 128, K=128 -> 128
    wprep<<<128, 256, 0, stream>>>(Ws0a, SC1b, SH1b, WB0a, BI0a, 384, 128);
    knn_kernel<<<dim3(8192 / 32, 4), 256, 0, stream>>>(p1, p2, 8192, 2048, IDX, WGT);
    build_x<<<(int)(((size_t)4 * 8192 * (384 / 4) + 255) / 256), 256, 0, stream>>>(
        F1T, FN1, IDX, WGT, XS, 128, 384, 256, 8192, 2048);
    gemm64<<<dim3(512, 2), 256, 0, stream>>>(XS, WB0a, BI0a, YA, PS, 32768, 384, 128);
    bn_finalize<<<128, 256, 0, stream>>>(PS, gs0a, bs0a, SC0a, SH0a, 512, 32768);
    wprep<<<128, 256, 0, stream>>>(Ws0b, SC0a, SH0a, WB0b, BI0b, 128, 0);
    gemm64<<<dim3(512, 2), 256, 0, stream>>>(YA, WB0b, BI0b, XO, PS, 32768, 128, 128);
    bn_finalize<<<128, 256, 0, stream>>>(PS, gs0b, bs0b, SC0b, SH0b, 512, 32768);

    out_bn_tr<<<dim3(8192 / 32, 128 / 32, 4), 256, 0, stream>>>(XO, OUT, SC0b, SH0b, 128, 8192);
}

// Round 7
// 199.954 us; speedup vs baseline: 6.1391x; 1.1012x over previous
//
#include <hip/hip_runtime.h>
#include <math.h>

#define BN_EPS 1e-5f

typedef float f32x4 __attribute__((ext_vector_type(4)));
typedef short s16x8 __attribute__((ext_vector_type(8)));
typedef short s16x4 __attribute__((ext_vector_type(4)));

__device__ __forceinline__ unsigned short f2bf(float f) {
    unsigned u = __builtin_bit_cast(unsigned, f);
    u = u + 0x7FFFu + ((u >> 16) & 1u);
    return (unsigned short)(u >> 16);
}
__device__ __forceinline__ float bf2f(unsigned short s) {
    unsigned u = ((unsigned)s) << 16;
    return __builtin_bit_cast(float, u);
}

__device__ __forceinline__ void gload16(const void* g, void* l) {
    __builtin_amdgcn_global_load_lds((const __attribute__((address_space(1))) unsigned int*)g,
                                     (__attribute__((address_space(3))) unsigned int*)l,
                                     16, 0, 0);
}

// ================ fused transposes (B,C,N) fp32 -> (B,N,C) bf16; cls MLP inlined in f1 segment ======
__global__ __launch_bounds__(256) void tr_all(const float* __restrict__ f1,
                                              const float* __restrict__ f2,
                                              const float* __restrict__ f3,
                                              const float* __restrict__ f4,
                                              unsigned short* __restrict__ F1T,
                                              unsigned short* __restrict__ F2T,
                                              unsigned short* __restrict__ F3T,
                                              unsigned short* __restrict__ F4T,
                                              const int* __restrict__ lbl,
                                              const float* __restrict__ Wc1,
                                              const float* __restrict__ gc,
                                              const float* __restrict__ bc,
                                              const float* __restrict__ Wc2) {
    __shared__ float t[32][33];
    __shared__ float clsv[32];
    __shared__ float hsh[4][64];
    __shared__ float actsh[4][64];
    int bx = blockIdx.x, b = blockIdx.y;
    const float* in; unsigned short* out; int C, N, nx, seg; bool docls = false;
    if (bx < 128)      { in = f4; out = F4T; C = 1024; N = 128;  nx = 4;   seg = bx; }
    else if (bx < 384) { in = f3; out = F3T; C = 512;  N = 512;  nx = 16;  seg = bx - 128; }
    else if (bx < 896) { in = f2; out = F2T; C = 256;  N = 2048; nx = 64;  seg = bx - 384; }
    else               { in = f1; out = F1T; C = 128;  N = 8192; nx = 256; seg = bx - 896; docls = true; }
    int n0 = (seg % nx) * 32, c0 = (seg / nx) * 32;
    int tid = threadIdx.x;
    if (docls) {
        { int b2 = tid >> 6, c = tid & 63; hsh[b2][c] = Wc1[c * 16 + lbl[b2]]; }
        __syncthreads();
        if (tid < 64) {
            int c = tid;
            float m = 0.f;
            for (int b2 = 0; b2 < 4; b2++) m += hsh[b2][c];
            m *= 0.25f;
            float v = 0.f;
            for (int b2 = 0; b2 < 4; b2++) { float d = hsh[b2][c] - m; v += d * d; }
            v *= 0.25f;
            float sc = gc[c] * rsqrtf(v + BN_EPS);
            float sh = bc[c] - m * sc;
            for (int b2 = 0; b2 < 4; b2++) {
                float x = hsh[b2][c] * sc + sh;
                actsh[b2][c] = 0.5f * x * (1.f + erff(x * 0.70710678118654752f));
            }
        }
        __syncthreads();
        if (tid < 32) {
            float s = 0.f;
            for (int c = 0; c < 64; c++) s += Wc2[(size_t)(c0 + tid) * 64 + c] * actsh[b][c];
            clsv[tid] = s;
        }
        __syncthreads();
    }
    int i = tid & 31, jj = tid >> 5;
#pragma unroll
    for (int j = jj; j < 32; j += 8) {
        float v = in[((size_t)b * C + c0 + j) * N + n0 + i];
        if (docls) v += clsv[j];
        t[j][i] = v;
    }
    __syncthreads();
    int j2 = tid & 31, i2b = tid >> 5;
#pragma unroll
    for (int i2 = i2b; i2 < 32; i2 += 8)
        out[((size_t)b * N + n0 + i2) * C + c0 + j2] = f2bf(t[j2][i2]);
}

// ================ fused 3-NN (all stages): consecutive-j chunks + b128 LDS + med3 insert ============
template<int N2, int CHUNK, int STRIDE>
__device__ __forceinline__ void knn_body(const float* __restrict__ pd,
                                         const float* __restrict__ ps,
                                         int N1, int grp, int b,
                                         int* __restrict__ idx, float* __restrict__ w,
                                         float* spx, float* spy, float* spz) {
    int tid = threadIdx.x;
    for (int g = tid; g < N2; g += 256) {
        int s = g / CHUNK, off = g % CHUNK;
        size_t base = ((size_t)b * N2 + g) * 3;
        spx[s * STRIDE + off] = ps[base];
        spy[s * STRIDE + off] = ps[base + 1];
        spz[s * STRIDE + off] = ps[base + 2];
    }
    __syncthreads();
    int sub = tid & 7;
    int n = grp * 32 + (tid >> 3);
    size_t pb = ((size_t)b * N1 + n) * 3;
    float px = pd[pb], py = pd[pb + 1], pz = pd[pb + 2];
    float dd0 = 3.4e38f, dd1 = 3.4e38f, dd2 = 3.4e38f;
    int ii0 = 0, ii1 = 0, ii2 = 0;
    const float* rx = spx + sub * STRIDE;
    const float* ry = spy + sub * STRIDE;
    const float* rz = spz + sub * STRIDE;
    int jbase = sub * CHUNK;
    for (int t = 0; t < CHUNK; t += 4) {
        f32x4 x4 = *(const f32x4*)(rx + t);
        f32x4 y4 = *(const f32x4*)(ry + t);
        f32x4 z4 = *(const f32x4*)(rz + t);
#pragma unroll
        for (int e = 0; e < 4; e++) {
            float dx = px - x4[e], dy = py - y4[e], dz = pz - z4[e];
            float d = dx * dx + dy * dy + dz * dz;
            int j = jbase + t + e;
            bool C0 = d < dd0, C1 = d < dd1, C2 = d < dd2;
            int ni2 = C1 ? ii1 : (C2 ? j : ii2);
            int ni1 = C0 ? ii0 : (C1 ? j : ii1);
            int ni0 = C0 ? j : ii0;
            dd2 = __builtin_amdgcn_fmed3f(d, dd1, dd2);
            dd1 = __builtin_amdgcn_fmed3f(d, dd0, dd1);
            dd0 = fminf(d, dd0);
            ii0 = ni0; ii1 = ni1; ii2 = ni2;
        }
    }
    // exact u64 butterfly merge across the 8 sub-lanes
    unsigned long long k0 = ((unsigned long long)__builtin_bit_cast(unsigned, dd0) << 32) | (unsigned)ii0;
    unsigned long long k1 = ((unsigned long long)__builtin_bit_cast(unsigned, dd1) << 32) | (unsigned)ii1;
    unsigned long long k2 = ((unsigned long long)__builtin_bit_cast(unsigned, dd2) << 32) | (unsigned)ii2;
#pragma unroll
    for (int m = 1; m < 8; m <<= 1) {
        unsigned long long e0, e1, e2;
        { int lo = __shfl_xor((int)(unsigned)(k0 & 0xFFFFFFFFull), m), hi = __shfl_xor((int)(unsigned)(k0 >> 32), m);
          e0 = ((unsigned long long)(unsigned)hi << 32) | (unsigned)lo; }
        { int lo = __shfl_xor((int)(unsigned)(k1 & 0xFFFFFFFFull), m), hi = __shfl_xor((int)(unsigned)(k1 >> 32), m);
          e1 = ((unsigned long long)(unsigned)hi << 32) | (unsigned)lo; }
        { int lo = __shfl_xor((int)(unsigned)(k2 & 0xFFFFFFFFull), m), hi = __shfl_xor((int)(unsigned)(k2 >> 32), m);
          e2 = ((unsigned long long)(unsigned)hi << 32) | (unsigned)lo; }
        unsigned long long t0, t1;
        t0 = k0 > e0 ? k0 : e0; k0 = k0 < e0 ? k0 : e0; t1 = k1 > t0 ? k1 : t0; k1 = k1 < t0 ? k1 : t0; k2 = k2 < t1 ? k2 : t1;
        t0 = k0 > e1 ? k0 : e1; k0 = k0 < e1 ? k0 : e1; t1 = k1 > t0 ? k1 : t0; k1 = k1 < t0 ? k1 : t0; k2 = k2 < t1 ? k2 : t1;
        t0 = k0 > e2 ? k0 : e2; k0 = k0 < e2 ? k0 : e2; t1 = k1 > t0 ? k1 : t0; k1 = k1 < t0 ? k1 : t0; k2 = k2 < t1 ? k2 : t1;
    }
    if (sub == 0) {
        float f0 = __builtin_bit_cast(float, (unsigned)(k0 >> 32));
        float f1 = __builtin_bit_cast(float, (unsigned)(k1 >> 32));
        float f2 = __builtin_bit_cast(float, (unsigned)(k2 >> 32));
        float w0 = 1.f / (f0 + 1e-8f), w1 = 1.f / (f1 + 1e-8f), w2 = 1.f / (f2 + 1e-8f);
        float s = 1.f / (w0 + w1 + w2);
        size_t o = ((size_t)b * N1 + n) * 3;
        idx[o] = (int)(unsigned)(k0 & 0xFFFFFFFFull);
        idx[o + 1] = (int)(unsigned)(k1 & 0xFFFFFFFFull);
        idx[o + 2] = (int)(unsigned)(k2 & 0xFFFFFFFFull);
        w[o] = w0 * s; w[o + 1] = w1 * s; w[o + 2] = w2 * s;
    }
}

__global__ __launch_bounds__(256) void knn_all(const float* __restrict__ p1,
                                               const float* __restrict__ p2,
                                               const float* __restrict__ p3,
                                               const float* __restrict__ p4,
                                               int* __restrict__ idx0, float* __restrict__ w0,
                                               int* __restrict__ idx1, float* __restrict__ w1,
                                               int* __restrict__ idx2, float* __restrict__ w2) {
    __shared__ float spx[8 * 264], spy[8 * 264], spz[8 * 264];
    int bx = blockIdx.x, b = blockIdx.y;
    if (bx < 16)      knn_body<128, 16, 24>(p3, p4, 512, bx, b, idx2, w2, spx, spy, spz);
    else if (bx < 80) knn_body<512, 64, 72>(p2, p3, 2048, bx - 16, b, idx1, w1, spx, spy, spz);
    else              knn_body<2048, 256, 264>(p1, p2, 8192, bx - 80, b, idx0, w0, spx, spy, spz);
}

// ================ build x (point-major, 16B wide): XS[b][n][c] = skipT | interp(fsT) ================
__global__ __launch_bounds__(256) void build_x(const unsigned short* __restrict__ skipT,
                                               const unsigned short* __restrict__ fsT,
                                               const int* __restrict__ idx,
                                               const float* __restrict__ w,
                                               unsigned short* __restrict__ x,
                                               int Cskip, int Ctot, int Csp, int N1, int N2) {
    int cq = Ctot >> 3;
    size_t gid = (size_t)blockIdx.x * 256 + threadIdx.x;
    if (gid >= (size_t)4 * N1 * cq) return;
    int c = (int)(gid % cq) * 8;
    int n = (int)((gid / cq) % N1);
    int b = (int)(gid / ((size_t)cq * N1));
    s16x8 o;
    if (c < Cskip) {
        o = *(const s16x8*)(skipT + ((size_t)b * N1 + n) * Cskip + c);
    } else {
        int c2 = c - Cskip;
        size_t ob = ((size_t)b * N1 + n) * 3;
        int i0 = idx[ob], i1 = idx[ob + 1], i2 = idx[ob + 2];
        float w0 = w[ob], w1 = w[ob + 1], w2 = w[ob + 2];
        s16x8 v0 = *(const s16x8*)(fsT + ((size_t)b * N2 + i0) * Csp + c2);
        s16x8 v1 = *(const s16x8*)(fsT + ((size_t)b * N2 + i1) * Csp + c2);
        s16x8 v2 = *(const s16x8*)(fsT + ((size_t)b * N2 + i2) * Csp + c2);
#pragma unroll
        for (int j = 0; j < 8; j++) {
            float v = w0 * bf2f((unsigned short)v0[j]) + w1 * bf2f((unsigned short)v1[j]) + w2 * bf2f((unsigned short)v2[j]);
            o[j] = (short)f2bf(v);
        }
    }
    *(s16x8*)(x + ((size_t)b * N1 + n) * Ctot + c) = o;
}

// ================ weight prep: fold per-k BN affine into weights; bf16 W + fp32 bias ================
__global__ __launch_bounds__(256) void wprep(const float* __restrict__ W,
                                             const float* __restrict__ sc,
                                             const float* __restrict__ sh,
                                             unsigned short* __restrict__ Wb,
                                             float* __restrict__ bias,
                                             int K, int kStart) {
    int m = blockIdx.x;
    int tid = threadIdx.x;
    float bsum = 0.f;
    for (int k = tid; k < K; k += 256) {
        float wv = W[(size_t)m * K + k];
        float o = wv;
        if (sc && k >= kStart) {
            o = wv * sc[k - kStart];
            bsum += wv * sh[k - kStart];
        }
        Wb[(size_t)m * K + k] = f2bf(o);
    }
    __shared__ float ls[256];
    ls[tid] = bsum;
    __syncthreads();
    for (int o = 128; o > 0; o >>= 1) {
        if (tid < o) ls[tid] += ls[tid + o];
        __syncthreads();
    }
    if (tid == 0) bias[m] = ls[0];
}

// ================ bf16 MFMA GEMM, 64x64 tile, dbuf + global_load_lds + counted vmcnt ================
__global__ __launch_bounds__(256) void gemm64(const unsigned short* __restrict__ XT,
                                              const unsigned short* __restrict__ Wb,
                                              const float* __restrict__ bias,
                                              unsigned short* __restrict__ OutT,
                                              float* __restrict__ ps,
                                              int BN, int K, int M) {
    __shared__ unsigned short As[2][64 * 32];
    __shared__ unsigned short Bs[2][64 * 32];
    __shared__ float sred[2][2][32][2];
    int tid = threadIdx.x;
    int lane = tid & 63, wid = tid >> 6;
    int wn = wid & 1, wm = wid >> 1;
    int bx = blockIdx.x, by = blockIdx.y;

    int srow = (wid << 4) + (lane >> 2);
    int skcol = (lane & 3) << 3;
    const unsigned short* gA = XT + (size_t)(bx * 64 + srow) * K + skcol;
    const unsigned short* gB = Wb + (size_t)(by * 64 + srow) * K + skcol;

    f32x4 acc[2][2];
#pragma unroll
    for (int i = 0; i < 2; i++)
#pragma unroll
        for (int j = 0; j < 2; j++) acc[i][j] = (f32x4)0.f;

    int nt = K >> 5;
    gload16(gA, &As[0][wid * 512]);
    gload16(gB, &Bs[0][wid * 512]);

    int r16 = lane & 15, q = lane >> 4;
    for (int t = 0; t < nt; t++) {
        int cur = t & 1;
        if (t + 1 < nt) {
            int k0 = (t + 1) << 5;
            gload16(gA + k0, &As[cur ^ 1][wid * 512]);
            gload16(gB + k0, &Bs[cur ^ 1][wid * 512]);
            asm volatile("s_waitcnt vmcnt(2)" ::: "memory");
        } else {
            asm volatile("s_waitcnt vmcnt(0)" ::: "memory");
        }
        __syncthreads();
        s16x8 afr[2], bfr[2];
        afr[0] = *(const s16x8*)&As[cur][(wn * 32 + r16) * 32 + q * 8];
        afr[1] = *(const s16x8*)&As[cur][(wn * 32 + 16 + r16) * 32 + q * 8];
        bfr[0] = *(const s16x8*)&Bs[cur][(wm * 32 + r16) * 32 + q * 8];
        bfr[1] = *(const s16x8*)&Bs[cur][(wm * 32 + 16 + r16) * 32 + q * 8];
        asm volatile("s_waitcnt lgkmcnt(0)" ::: "memory");
        __builtin_amdgcn_sched_barrier(0);
        __syncthreads();
#pragma unroll
        for (int i = 0; i < 2; i++)
#pragma unroll
            for (int j = 0; j < 2; j++)
                acc[i][j] = __builtin_amdgcn_mfma_f32_16x16x32_bf16(afr[i], bfr[j], acc[i][j], 0, 0, 0);
    }

    int mc0 = by * 64 + wm * 32 + r16;
    float bv[2] = { bias[mc0], bias[mc0 + 16] };
    unsigned short* Ob = OutT + (size_t)(bx * 64) * M + by * 64;
    float s[2] = {0.f, 0.f}, qq[2] = {0.f, 0.f};
#pragma unroll
    for (int i = 0; i < 2; i++) {
#pragma unroll
        for (int j = 0; j < 2; j++) {
            int mcol = wm * 32 + j * 16 + r16;
#pragma unroll
            for (int r = 0; r < 4; r++) {
                float v = acc[i][j][r] + bv[j];
                s[j] += v; qq[j] += v * v;
                int n = wn * 32 + i * 16 + q * 4 + r;
                Ob[(size_t)n * M + mcol] = f2bf(v);
            }
        }
    }
#pragma unroll
    for (int j = 0; j < 2; j++) {
        s[j] += __shfl_xor(s[j], 16); s[j] += __shfl_xor(s[j], 32);
        qq[j] += __shfl_xor(qq[j], 16); qq[j] += __shfl_xor(qq[j], 32);
    }
    if (lane < 16) {
#pragma unroll
        for (int j = 0; j < 2; j++) {
            sred[wn][wm][j * 16 + lane][0] = s[j];
            sred[wn][wm][j * 16 + lane][1] = qq[j];
        }
    }
    __syncthreads();
    if (tid < 64) {
        int wmm = tid >> 5, c = tid & 31;
        float ssum = sred[0][wmm][c][0] + sred[1][wmm][c][0];
        float qsum = sred[0][wmm][c][1] + sred[1][wmm][c][1];
        size_t blin = (size_t)by * gridDim.x + bx;
        ps[blin * 128 + tid * 2] = ssum;
        ps[blin * 128 + tid * 2 + 1] = qsum;
    }
}

// ================ finalize BN: one block per channel ================
__global__ __launch_bounds__(256) void bn_finalize(const float* __restrict__ ps,
                                                   const float* __restrict__ g,
                                                   const float* __restrict__ bb,
                                                   float* __restrict__ sc,
                                                   float* __restrict__ sh,
                                                   int gx, int Npts) {
    int m = blockIdx.x;
    int by = m >> 6, ch = m & 63;
    float s = 0.f, q = 0.f;
    for (int bxi = threadIdx.x; bxi < gx; bxi += 256) {
        size_t blin = (size_t)by * gx + bxi;
        s += ps[blin * 128 + ch * 2];
        q += ps[blin * 128 + ch * 2 + 1];
    }
    __shared__ float ls[256], lq[256];
    ls[threadIdx.x] = s; lq[threadIdx.x] = q;
    __syncthreads();
    for (int o = 128; o > 0; o >>= 1) {
        if (threadIdx.x < o) { ls[threadIdx.x] += ls[threadIdx.x + o]; lq[threadIdx.x] += lq[threadIdx.x + o]; }
        __syncthreads();
    }
    if (threadIdx.x == 0) {
        float inv = 1.f / (float)Npts;
        float mean = ls[0] * inv;
        float var = fmaxf(lq[0] * inv - mean * mean, 0.f);
        float scale = g[m] * rsqrtf(var + BN_EPS);
        sc[m] = scale;
        sh[m] = bb[m] - mean * scale;
    }
}

// ================ final: (B,N,M) bf16 -> (B,M,N) fp32 with BN affine ================
__global__ __launch_bounds__(256) void out_bn_tr(const unsigned short* __restrict__ in,
                                                 float* __restrict__ out,
                                                 const float* __restrict__ sc,
                                                 const float* __restrict__ sh,
                                                 int M, int N) {
    __shared__ float t[32][33];
    int b = blockIdx.z;
    int n0 = blockIdx.x * 32, m0 = blockIdx.y * 32;
    int j = threadIdx.x & 31, ii = threadIdx.x >> 5;
#pragma unroll
    for (int i = ii; i < 32; i += 8)
        t[i][j] = bf2f(in[((size_t)b * N + n0 + i) * M + m0 + j]);
    __syncthreads();
    int i2 = threadIdx.x & 31, j2b = threadIdx.x >> 5;
#pragma unroll
    for (int j2 = j2b; j2 < 32; j2 += 8)
        out[((size_t)b * M + m0 + j2) * N + n0 + i2] = t[i2][j2] * sc[m0 + j2] + sh[m0 + j2];
}

extern "C" void kernel_launch(void* const* d_in, const int* in_sizes, int n_in,
                              void* d_out, int out_size, void* d_ws, size_t ws_size,
                              hipStream_t stream) {
    const float* p1 = (const float*)d_in[1];
    const float* p2 = (const float*)d_in[2];
    const float* p3 = (const float*)d_in[3];
    const float* p4 = (const float*)d_in[4];
    const float* f1 = (const float*)d_in[5];
    const float* f2 = (const float*)d_in[6];
    const float* f3 = (const float*)d_in[7];
    const float* f4 = (const float*)d_in[8];
    const int* cls = (const int*)d_in[9];
    const float* Wc1 = (const float*)d_in[10];
    const float* gc  = (const float*)d_in[11];
    const float* bc  = (const float*)d_in[12];
    const float* Wc2 = (const float*)d_in[13];
    const float* Ws2a = (const float*)d_in[14];
    const float* gs2a = (const float*)d_in[15];
    const float* bs2a = (const float*)d_in[16];
    const float* Ws2b = (const float*)d_in[17];
    const float* gs2b = (const float*)d_in[18];
    const float* bs2b = (const float*)d_in[19];
    const float* Ws1a = (const float*)d_in[20];
    const float* gs1a = (const float*)d_in[21];
    const float* bs1a = (const float*)d_in[22];
    const float* Ws1b = (const float*)d_in[23];
    const float* gs1b = (const float*)d_in[24];
    const float* bs1b = (const float*)d_in[25];
    const float* Ws0a = (const float*)d_in[26];
    const float* gs0a = (const float*)d_in[27];
    const float* bs0a = (const float*)d_in[28];
    const float* Ws0b = (const float*)d_in[29];
    const float* gs0b = (const float*)d_in[30];
    const float* bs0b = (const float*)d_in[31];

    char* ws = (char*)d_ws;
    size_t off = 0;
    auto alloc = [&](size_t bytes) { char* p = ws + off; off += (bytes + 255) & ~(size_t)255; return p; };
    unsigned short* F4T = (unsigned short*)alloc((size_t)4 * 128 * 1024 * 2);
    unsigned short* F3T = (unsigned short*)alloc((size_t)4 * 512 * 512 * 2);
    unsigned short* F2T = (unsigned short*)alloc((size_t)4 * 2048 * 256 * 2);
    unsigned short* F1T = (unsigned short*)alloc((size_t)4 * 8192 * 128 * 2);
    unsigned short* XS  = (unsigned short*)alloc((size_t)4 * 8192 * 384 * 2);
    unsigned short* YA  = (unsigned short*)alloc((size_t)4 * 8192 * 128 * 2);
    unsigned short* FN2 = (unsigned short*)alloc((size_t)4 * 512 * 512 * 2);
    unsigned short* FN1 = (unsigned short*)alloc((size_t)4 * 2048 * 256 * 2);
    unsigned short* XO  = (unsigned short*)alloc((size_t)4 * 8192 * 128 * 2);
    unsigned short* WB2a = (unsigned short*)alloc((size_t)512 * 1536 * 2);
    unsigned short* WB2b = (unsigned short*)alloc((size_t)512 * 512 * 2);
    unsigned short* WB1a = (unsigned short*)alloc((size_t)256 * 768 * 2);
    unsigned short* WB1b = (unsigned short*)alloc((size_t)256 * 256 * 2);
    unsigned short* WB0a = (unsigned short*)alloc((size_t)128 * 384 * 2);
    unsigned short* WB0b = (unsigned short*)alloc((size_t)128 * 128 * 2);
    float* BI2a = (float*)alloc(512 * 4); float* BI2b = (float*)alloc(512 * 4);
    float* BI1a = (float*)alloc(256 * 4); float* BI1b = (float*)alloc(256 * 4);
    float* BI0a = (float*)alloc(128 * 4); float* BI0b = (float*)alloc(128 * 4);
    int*   IDX0 = (int*)alloc((size_t)4 * 8192 * 3 * 4);
    float* WGT0 = (float*)alloc((size_t)4 * 8192 * 3 * 4);
    int*   IDX1 = (int*)alloc((size_t)4 * 2048 * 3 * 4);
    float* WGT1 = (float*)alloc((size_t)4 * 2048 * 3 * 4);
    int*   IDX2 = (int*)alloc((size_t)4 * 512 * 3 * 4);
    float* WGT2 = (float*)alloc((size_t)4 * 512 * 3 * 4);
    float* PS = (float*)alloc((size_t)1024 * 128 * 4);
    float* SC2a = (float*)alloc(512 * 4); float* SH2a = (float*)alloc(512 * 4);
    float* SC2b = (float*)alloc(512 * 4); float* SH2b = (float*)alloc(512 * 4);
    float* SC1a = (float*)alloc(512 * 4); float* SH1a = (float*)alloc(512 * 4);
    float* SC1b = (float*)alloc(512 * 4); float* SH1b = (float*)alloc(512 * 4);
    float* SC0a = (float*)alloc(512 * 4); float* SH0a = (float*)alloc(512 * 4);
    float* SC0b = (float*)alloc(512 * 4); float* SH0b = (float*)alloc(512 * 4);
    float* OUT = (float*)d_out;

    // fused transposes (+inline cls) and fused KNN for all stages
    tr_all<<<dim3(1920, 4), 256, 0, stream>>>(f1, f2, f3, f4, F1T, F2T, F3T, F4T, cls, Wc1, gc, bc, Wc2);
    knn_all<<<dim3(336, 4), 256, 0, stream>>>(p1, p2, p3, p4, IDX0, WGT0, IDX1, WGT1, IDX2, WGT2);

    // ---- stage s2: BN=2048 rows, K=1536 -> M=512, then K=512 -> 512
    wprep<<<512, 256, 0, stream>>>(Ws2a, nullptr, nullptr, WB2a, BI2a, 1536, 0);
    build_x<<<(int)(((size_t)4 * 512 * (1536 / 8) + 255) / 256), 256, 0, stream>>>(
        F3T, F4T, IDX2, WGT2, XS, 512, 1536, 1024, 512, 128);
    gemm64<<<dim3(32, 8), 256, 0, stream>>>(XS, WB2a, BI2a, YA, PS, 2048, 1536, 512);
    bn_finalize<<<512, 256, 0, stream>>>(PS, gs2a, bs2a, SC2a, SH2a, 32, 2048);
    wprep<<<512, 256, 0, stream>>>(Ws2b, SC2a, SH2a, WB2b, BI2b, 512, 0);
    gemm64<<<dim3(32, 8), 256, 0, stream>>>(YA, WB2b, BI2b, FN2, PS, 2048, 512, 512);
    bn_finalize<<<512, 256, 0, stream>>>(PS, gs2b, bs2b, SC2b, SH2b, 32, 2048);

    // ---- stage s1: BN=8192 rows, K=768 -> 256, K=256 -> 256
    wprep<<<256, 256, 0, stream>>>(Ws1a, SC2b, SH2b, WB1a, BI1a, 768, 256);
    build_x<<<(int)(((size_t)4 * 2048 * (768 / 8) + 255) / 256), 256, 0, stream>>>(
        F2T, FN2, IDX1, WGT1, XS, 256, 768, 512, 2048, 512);
    gemm64<<<dim3(128, 4), 256, 0, stream>>>(XS, WB1a, BI1a, YA, PS, 8192, 768, 256);
    bn_finalize<<<256, 256, 0, stream>>>(PS, gs1a, bs1a, SC1a, SH1a, 128, 8192);
    wprep<<<256, 256, 0, stream>>>(Ws1b, SC1a, SH1a, WB1b, BI1b, 256, 0);
    gemm64<<<dim3(128, 4), 256, 0, stream>>>(YA, WB1b, BI1b, FN1, PS, 8192, 256, 256);
    bn_finalize<<<256, 256, 0, stream>>>(PS, gs1b, bs1b, SC1b, SH1b, 128, 8192);

    // ---- stage s0: BN=32768 rows, K=384 -> 128, K=128 -> 128
    wprep<<<128, 256, 0, stream>>>(Ws0a, SC1b, SH1b, WB0a, BI0a, 384, 128);
    build_x<<<(int)(((size_t)4 * 8192 * (384 / 8) + 255) / 256), 256, 0, stream>>>(
        F1T, FN1, IDX0, WGT0, XS, 128, 384, 256, 8192, 2048);
    gemm64<<<dim3(512, 2), 256, 0, stream>>>(XS, WB0a, BI0a, YA, PS, 32768, 384, 128);
    bn_finalize<<<128, 256, 0, stream>>>(PS, gs0a, bs0a, SC0a, SH0a, 512, 32768);
    wprep<<<128, 256, 0, stream>>>(Ws0b, SC0a, SH0a, WB0b, BI0b, 128, 0);
    gemm64<<<dim3(512, 2), 256, 0, stream>>>(YA, WB0b, BI0b, XO, PS, 32768, 128, 128);
    bn_finalize<<<128, 256, 0, stream>>>(PS, gs0b, bs0b, SC0b, SH0b, 512, 32768);

    out_bn_tr<<<dim3(8192 / 32, 128 / 32, 4), 256, 0, stream>>>(XO, OUT, SC0b, SH0b, 128, 8192);
}